// Round 5
// baseline (262.972 us; speedup 1.0000x reference)
//
#include <hip/hip_runtime.h>
#include <cstddef>

#define E 512
#define H 8
#define D 64
#define BATCH 2
#define SEQ 4096

typedef __attribute__((ext_vector_type(8))) short bf16x8;   // MFMA A/B frag
typedef __attribute__((ext_vector_type(4))) float f32x4;    // 16x16 C/D frag
typedef __attribute__((ext_vector_type(16))) float f32x16;  // 32x32 C/D frag
typedef __attribute__((ext_vector_type(4))) unsigned uint4v;

__device__ __forceinline__ ushort f2bf(float f) {
  unsigned u = __builtin_bit_cast(unsigned, f);
  u += 0x7fff + ((u >> 16) & 1);  // RNE
  return (ushort)(u >> 16);
}
__device__ __forceinline__ float bf2f(ushort h) {
  return __builtin_bit_cast(float, (unsigned)h << 16);
}
__device__ __forceinline__ unsigned pk_bf16(float lo, float hi) {
#if __has_builtin(__builtin_amdgcn_cvt_pk_bf16_f32)
  typedef __attribute__((ext_vector_type(2))) __bf16 bfv2;
  bfv2 r = __builtin_amdgcn_cvt_pk_bf16_f32(lo, hi);
  return __builtin_bit_cast(unsigned, r);
#else
  return (unsigned)f2bf(lo) | ((unsigned)f2bf(hi) << 16);
#endif
}
__device__ __forceinline__ float fexp2(float x) {
#if __has_builtin(__builtin_amdgcn_exp2f)
  return __builtin_amdgcn_exp2f(x);
#else
  return exp2f(x);
#endif
}
// lanes[32:63] of a  <->  lanes[0:31] of b. NON-volatile: scheduler may
// move it (we want softmax(t1) to slide under PV(t0) MFMAs).
__device__ __forceinline__ void permswap32(unsigned& a, unsigned& b) {
  asm("v_permlane32_swap_b32 %0, %1" : "+v"(a), "+v"(b));
}

// ---------------------------------------------------------------------------
// Kernel 0: cast x -> bf16 hi/lo split (xh + xl ~= x to ~16 mantissa bits)
// ---------------------------------------------------------------------------
__global__ __launch_bounds__(256) void xcast(const float* __restrict__ x,
                                             ushort* __restrict__ xh,
                                             ushort* __restrict__ xl) {
  size_t i = ((size_t)blockIdx.x * 256 + threadIdx.x) * 4;
  float4 v = *(const float4*)&x[i];
  ushort4 h, l;
  h.x = f2bf(v.x); l.x = f2bf(v.x - bf2f(h.x));
  h.y = f2bf(v.y); l.y = f2bf(v.y - bf2f(h.y));
  h.z = f2bf(v.z); l.z = f2bf(v.z - bf2f(h.z));
  h.w = f2bf(v.w); l.w = f2bf(v.w - bf2f(h.w));
  *(ushort4*)&xh[i] = h;
  *(ushort4*)&xl[i] = l;
}

// ---------------------------------------------------------------------------
// Kernel 1a: fold weights. Block = 256 k-lanes x 8 n (8 fp32 accs).
// ---------------------------------------------------------------------------
__global__ __launch_bounds__(256) void fold_tiled(
    const float* __restrict__ wq, const float* __restrict__ wk,
    const float* __restrict__ rot, const float* __restrict__ ent,
    ushort* __restrict__ weffbT) {
  const int which = blockIdx.z;
  const float* w = which ? wk : wq;
  const float* r = which ? ent : rot;
  const int k = blockIdx.x * 256 + threadIdx.x;
  const int n0 = blockIdx.y * 8;
  float acc[8] = {};
  for (int j0 = 0; j0 < E; j0 += 16) {
    float wv_[16];
#pragma unroll
    for (int u = 0; u < 16; ++u) wv_[u] = w[(size_t)(j0 + u) * E + k];
#pragma unroll
    for (int u = 0; u < 16; ++u)
#pragma unroll
      for (int t = 0; t < 8; ++t)
        acc[t] += wv_[u] * r[(size_t)(j0 + u) * E + n0 + t];
  }
#pragma unroll
  for (int t = 0; t < 8; ++t)
    weffbT[(size_t)which * E * E + (size_t)(n0 + t) * E + k] = f2bf(acc[t]);
}

// Kernel 1b: weffT[2][n][k] = bf16(wv[n][k]) — identity layout, pure cast.
__global__ __launch_bounds__(256) void wv_cast(const float* __restrict__ wv,
                                               ushort* __restrict__ dst) {
  size_t i = ((size_t)blockIdx.x * 256 + threadIdx.x) * 4;
  float4 v = *(const float4*)&wv[i];
  ushort4 o;
  o.x = f2bf(v.x); o.y = f2bf(v.y); o.z = f2bf(v.z); o.w = f2bf(v.w);
  *(ushort4*)&dst[i] = o;
}

// ---------------------------------------------------------------------------
// Kernel 2: fused QKV GEMM (unchanged; software-pipelined staging).
// ---------------------------------------------------------------------------
#define LDA 40  // padded LDS stride (bf16): 80B

__global__ __launch_bounds__(256) void qkv_fused(
    const ushort* __restrict__ xhg, const ushort* __restrict__ xlg,
    const ushort* __restrict__ weffbT, ushort* __restrict__ qg,
    ushort* __restrict__ kg, ushort* __restrict__ vtg) {
  __shared__ ushort sm[5 * 64 * LDA];  // Ah | Al | B0 | B1 | B2
  ushort* Ah = sm;
  ushort* Al = sm + 64 * LDA;
  ushort* Bs = sm + 2 * 64 * LDA;
  ushort* vt_tile = Bs;  // epilogue reuse: 64*72 <= 3*64*40

  const int head = blockIdx.x;
  const int m0 = blockIdx.y * 64;
  const int tid = threadIdx.x;
  const int wave = tid >> 6, lane = tid & 63;
  const int l15 = lane & 15, quad = lane >> 4;
  const int ar = tid >> 2, ac8 = (tid & 3) * 8;  // 64x32 tile staging slot

  const ushort* arow = xhg + (size_t)(m0 + ar) * E + ac8;
  const ushort* lrow = xlg + (size_t)(m0 + ar) * E + ac8;
  const ushort* b0row = weffbT + (size_t)(head * 64 + ar) * E + ac8;

  f32x4 acc[3][4];
#pragma unroll
  for (int w = 0; w < 3; ++w)
#pragma unroll
    for (int nt = 0; nt < 4; ++nt) acc[w][nt] = (f32x4){0.f, 0.f, 0.f, 0.f};

  // preload tile k0=0
  uint4 pa_h = *(const uint4*)&arow[0];
  uint4 pa_l = *(const uint4*)&lrow[0];
  uint4 pb0 = *(const uint4*)&b0row[0];
  uint4 pb1 = *(const uint4*)&b0row[E * E];
  uint4 pb2 = *(const uint4*)&b0row[2 * E * E];

  for (int k0 = 0; k0 < E; k0 += 32) {
    __syncthreads();
    *(uint4*)&Ah[ar * LDA + ac8] = pa_h;
    *(uint4*)&Al[ar * LDA + ac8] = pa_l;
    *(uint4*)&Bs[0 * 64 * LDA + ar * LDA + ac8] = pb0;
    *(uint4*)&Bs[1 * 64 * LDA + ar * LDA + ac8] = pb1;
    *(uint4*)&Bs[2 * 64 * LDA + ar * LDA + ac8] = pb2;
    __syncthreads();

    const int kn = (k0 + 32 < E) ? k0 + 32 : 0;
    pa_h = *(const uint4*)&arow[kn];
    pa_l = *(const uint4*)&lrow[kn];
    pb0 = *(const uint4*)&b0row[kn];
    pb1 = *(const uint4*)&b0row[E * E + kn];
    pb2 = *(const uint4*)&b0row[2 * E * E + kn];

    bf16x8 ah = *(const bf16x8*)&Ah[(wave * 16 + l15) * LDA + quad * 8];
    bf16x8 al = *(const bf16x8*)&Al[(wave * 16 + l15) * LDA + quad * 8];
#pragma unroll
    for (int w = 0; w < 3; ++w)
#pragma unroll
      for (int nt = 0; nt < 4; ++nt) {
        bf16x8 bf = *(const bf16x8*)&Bs[w * 64 * LDA + (nt * 16 + l15) * LDA +
                                        quad * 8];
        acc[w][nt] =
            __builtin_amdgcn_mfma_f32_16x16x32_bf16(ah, bf, acc[w][nt], 0, 0, 0);
        acc[w][nt] =
            __builtin_amdgcn_mfma_f32_16x16x32_bf16(al, bf, acc[w][nt], 0, 0, 0);
      }
  }

  const int b = m0 >> 12;
  const int s_base = m0 & (SEQ - 1);
  const float QSCALE = 0.125f * 1.44269504f;  // fold 1/sqrt(D)*log2(e) into q

#pragma unroll
  for (int w = 0; w < 2; ++w) {
    ushort* dst = (w == 0) ? qg : kg;
    float sc = (w == 0) ? QSCALE : 1.0f;
#pragma unroll
    for (int nt = 0; nt < 4; ++nt)
#pragma unroll
      for (int r = 0; r < 4; ++r) {
        float v = acc[w][nt][r] * sc;
        float vo = __shfl_xor(v, 1);
        if (!(lane & 1)) {
          int s = s_base + wave * 16 + quad * 4 + r;
          size_t ix = ((size_t)(b * H + head) * SEQ + s) * D + nt * 16 + l15;
          *(unsigned*)&dst[ix] = pk_bf16(v, vo);
        }
      }
  }

  __syncthreads();  // Bs frag reads done in all waves before reuse
#pragma unroll
  for (int nt = 0; nt < 4; ++nt) {
    uint2 w2;
    w2.x = pk_bf16(acc[2][nt][0], acc[2][nt][1]);
    w2.y = pk_bf16(acc[2][nt][2], acc[2][nt][3]);
    *(uint2*)&vt_tile[(nt * 16 + l15) * 72 + wave * 16 + quad * 4] = w2;
  }
  __syncthreads();
  {
    int vr = tid >> 2, vs = (tid & 3) * 16;
    uint4 c0 = *(const uint4*)&vt_tile[vr * 72 + vs];
    uint4 c1 = *(const uint4*)&vt_tile[vr * 72 + vs + 8];
    size_t vo = ((size_t)(b * H + head) * D + vr) * SEQ + s_base + vs;
    *(uint4*)&vtg[vo] = c0;
    *(uint4*)&vtg[vo + 8] = c1;
  }
}

// ---------------------------------------------------------------------------
// Kernel 3: flash attention. Round-4 ILP body (interleaved QK chains,
// pipelined sm(t0)->PV(t0)->sm(t1)->PV(t1), P in registers) combined with
// round-1 in-block K-split (8 waves = 2 k-groups x 4 q-waves) to double
// resident waves: TLP (occupancy 18->35%) x ILP (2 chains/wave).
//
// Layouts (verified mappings, guide §3):
//   C 32x32: col = lane&31, row = (reg&3) + 8*(reg>>2) + 4*(lane>>5)
//   A 32x32x16: lane holds A[row=lane&31][c=(lane>>5)*8 + j], j=0..7
//   B 32x32x16: lane holds B[c=(lane>>5)*8 + j][col=lane&31]
// ---------------------------------------------------------------------------
#define LDK 72  // padded stride (bf16): 144B, 16B-aligned

__global__ __launch_bounds__(512, 4) void attn_mfma(
    const ushort* __restrict__ qg, const ushort* __restrict__ kg,
    const ushort* __restrict__ vtg, float* __restrict__ out) {
  __shared__ ushort sm[4 * 64 * LDK + 256];  // Ks[2] | Vs[2] | lex
  ushort* Ks0 = sm;
  ushort* Vs0 = sm + 2 * 64 * LDK;
  float* lex = (float*)(sm + 4 * 64 * LDK);  // 128 floats

  const int qt = blockIdx.x;  // 0..31 (128 q-rows each)
  const int bh = blockIdx.y;
  const int tid = threadIdx.x;
  const int wave = tid >> 6;  // 0..7
  const int grp = wave >> 2, wq = wave & 3;
  const int lane = tid & 63;
  const int l31 = lane & 31, hi = lane >> 5;
  const int gtid = tid & 255;  // tid within group

  const ushort* qp = qg + (size_t)bh * SEQ * D;
  const ushort* kp = kg + (size_t)bh * SEQ * D;
  const ushort* vp = vtg + (size_t)bh * D * SEQ;
  ushort* Ksg = Ks0 + grp * 64 * LDK;
  ushort* Vsg = Vs0 + grp * 64 * LDK;

  const int qrow0 = qt * 128 + wq * 32;
  // Q as B-operand: qf[ds] lane holds Q[qrow0+l31][ds*16 + hi*8 + j]
  bf16x8 qf[4];
#pragma unroll
  for (int ds = 0; ds < 4; ++ds)
    qf[ds] =
        *(const bf16x8*)&qp[(size_t)(qrow0 + l31) * D + ds * 16 + hi * 8];

  f32x16 o[2];
  o[0] = 0.f;
  o[1] = 0.f;
  float l_r = 0.f;  // per-lane partial row-sum for q = qrow0 + l31

  // staging: each group's 256 threads cover its 64x64 K and V tiles
  const int r0 = gtid >> 3, c0 = (gtid & 7) * 8;  // r0 in 0..31
  const int r1 = 32 + r0;

  // preload tile it=0 (kt = grp)
  uint4 pk0 = *(const uint4*)&kp[(size_t)(grp * 64 + r0) * D + c0];
  uint4 pk1 = *(const uint4*)&kp[(size_t)(grp * 64 + r1) * D + c0];
  uint4 pv0 = *(const uint4*)&vp[(size_t)r0 * SEQ + grp * 64 + c0];
  uint4 pv1 = *(const uint4*)&vp[(size_t)r1 * SEQ + grp * 64 + c0];

  for (int it = 0; it < SEQ / 128; ++it) {
    __syncthreads();  // prev iter's frag reads done (both groups)
    *(uint4*)&Ksg[r0 * LDK + c0] = pk0;
    *(uint4*)&Ksg[r1 * LDK + c0] = pk1;
    *(uint4*)&Vsg[r0 * LDK + c0] = pv0;
    *(uint4*)&Vsg[r1 * LDK + c0] = pv1;
    __syncthreads();

    // issue NEXT tile's loads; latency hides under this tile's compute
    {
      const int itn = (it + 1 < SEQ / 128) ? it + 1 : it;
      const int ktn = itn * 2 + grp;
      const ushort* ksrc = kp + (size_t)ktn * 64 * D;
      pk0 = *(const uint4*)&ksrc[r0 * D + c0];
      pk1 = *(const uint4*)&ksrc[r1 * D + c0];
      pv0 = *(const uint4*)&vp[(size_t)r0 * SEQ + ktn * 64 + c0];
      pv1 = *(const uint4*)&vp[(size_t)r1 * SEQ + ktn * 64 + c0];
    }

    __builtin_amdgcn_s_setprio(1);
    // ---- QK for BOTH 32-k subtiles, chains interleaved ----
    f32x16 st0 = 0.f, st1 = 0.f;
#pragma unroll
    for (int ds = 0; ds < 4; ++ds) {
      bf16x8 kf0 = *(const bf16x8*)&Ksg[(l31)*LDK + ds * 16 + hi * 8];
      bf16x8 kf1 = *(const bf16x8*)&Ksg[(32 + l31) * LDK + ds * 16 + hi * 8];
      st0 = __builtin_amdgcn_mfma_f32_32x32x16_bf16(kf0, qf[ds], st0, 0, 0, 0);
      st1 = __builtin_amdgcn_mfma_f32_32x32x16_bf16(kf1, qf[ds], st1, 0, 0, 0);
    }

    // ---- t = 0: softmax + P-frag build + PV ----
    bf16x8 pf00, pf01;
    {
      float pv[16];
#pragma unroll
      for (int r = 0; r < 16; ++r) pv[r] = fexp2(st0[r]);
      float s01 = (pv[0] + pv[1]) + (pv[2] + pv[3]);
      float s23 = (pv[4] + pv[5]) + (pv[6] + pv[7]);
      float s45 = (pv[8] + pv[9]) + (pv[10] + pv[11]);
      float s67 = (pv[12] + pv[13]) + (pv[14] + pv[15]);
      l_r += (s01 + s23) + (s45 + s67);
      unsigned w0[4], w1[4];
#pragma unroll
      for (int j = 0; j < 2; ++j) {
        {
          unsigned c0w = pk_bf16(pv[2 * j + 0], pv[2 * j + 1]);
          unsigned c1w = pk_bf16(pv[2 * j + 4], pv[2 * j + 5]);
          permswap32(c0w, c1w);
          w0[j] = c0w;
          w0[2 + j] = c1w;
        }
        {
          unsigned c0w = pk_bf16(pv[2 * j + 8], pv[2 * j + 9]);
          unsigned c1w = pk_bf16(pv[2 * j + 12], pv[2 * j + 13]);
          permswap32(c0w, c1w);
          w1[j] = c0w;
          w1[2 + j] = c1w;
        }
      }
      pf00 = __builtin_bit_cast(bf16x8, (uint4v){w0[0], w0[1], w0[2], w0[3]});
      pf01 = __builtin_bit_cast(bf16x8, (uint4v){w1[0], w1[1], w1[2], w1[3]});
    }
#pragma unroll
    for (int nt = 0; nt < 2; ++nt) {
      bf16x8 vf0 = *(const bf16x8*)&Vsg[(nt * 32 + l31) * LDK + hi * 8];
      o[nt] =
          __builtin_amdgcn_mfma_f32_32x32x16_bf16(pf00, vf0, o[nt], 0, 0, 0);
      bf16x8 vf1 = *(const bf16x8*)&Vsg[(nt * 32 + l31) * LDK + 16 + hi * 8];
      o[nt] =
          __builtin_amdgcn_mfma_f32_32x32x16_bf16(pf01, vf1, o[nt], 0, 0, 0);
    }

    // ---- t = 1: softmax (scheduler may overlap with PV(t0)) + PV ----
    bf16x8 pf10, pf11;
    {
      float pv[16];
#pragma unroll
      for (int r = 0; r < 16; ++r) pv[r] = fexp2(st1[r]);
      float s01 = (pv[0] + pv[1]) + (pv[2] + pv[3]);
      float s23 = (pv[4] + pv[5]) + (pv[6] + pv[7]);
      float s45 = (pv[8] + pv[9]) + (pv[10] + pv[11]);
      float s67 = (pv[12] + pv[13]) + (pv[14] + pv[15]);
      l_r += (s01 + s23) + (s45 + s67);
      unsigned w0[4], w1[4];
#pragma unroll
      for (int j = 0; j < 2; ++j) {
        {
          unsigned c0w = pk_bf16(pv[2 * j + 0], pv[2 * j + 1]);
          unsigned c1w = pk_bf16(pv[2 * j + 4], pv[2 * j + 5]);
          permswap32(c0w, c1w);
          w0[j] = c0w;
          w0[2 + j] = c1w;
        }
        {
          unsigned c0w = pk_bf16(pv[2 * j + 8], pv[2 * j + 9]);
          unsigned c1w = pk_bf16(pv[2 * j + 12], pv[2 * j + 13]);
          permswap32(c0w, c1w);
          w1[j] = c0w;
          w1[2 + j] = c1w;
        }
      }
      pf10 = __builtin_bit_cast(bf16x8, (uint4v){w0[0], w0[1], w0[2], w0[3]});
      pf11 = __builtin_bit_cast(bf16x8, (uint4v){w1[0], w1[1], w1[2], w1[3]});
    }
#pragma unroll
    for (int nt = 0; nt < 2; ++nt) {
      bf16x8 vf0 = *(const bf16x8*)&Vsg[(nt * 32 + l31) * LDK + 32 + hi * 8];
      o[nt] =
          __builtin_amdgcn_mfma_f32_32x32x16_bf16(pf10, vf0, o[nt], 0, 0, 0);
      bf16x8 vf1 = *(const bf16x8*)&Vsg[(nt * 32 + l31) * LDK + 48 + hi * 8];
      o[nt] =
          __builtin_amdgcn_mfma_f32_32x32x16_bf16(pf11, vf1, o[nt], 0, 0, 0);
    }
    __builtin_amdgcn_s_setprio(0);
  }

  // ---- combine the two K-halves (additive: no max bookkeeping) ----
  __syncthreads();  // all waves done with Ks/Vs before Oex overlay
  float lg = l_r + __shfl_xor(l_r, 32);  // lanes l/l+32 cover all 32 k-rows
  float* Oex = (float*)sm;               // [128 q][64 d], stride 68 floats
  if (grp == 1) {
#pragma unroll
    for (int nt = 0; nt < 2; ++nt)
#pragma unroll
      for (int r = 0; r < 16; ++r) {
        int row = (r & 3) + 8 * (r >> 2) + 4 * hi;
        Oex[(wq * 32 + row) * 68 + nt * 32 + l31] = o[nt][r];
      }
    if (lane < 32) lex[wq * 32 + l31] = lg;
  }
  __syncthreads();
  if (grp == 0) {
    float linv = 1.f / (lg + lex[wq * 32 + l31]);
    const int b = bh >> 3, h = bh & 7;
#pragma unroll
    for (int r = 0; r < 16; ++r) {
      int row = (r & 3) + 8 * (r >> 2) + 4 * hi;
      float inv = __shfl(linv, row);  // lane `row` owns q = qrow0 + row
      int srow = qt * 128 + wq * 32 + row;
#pragma unroll
      for (int nt = 0; nt < 2; ++nt) {
        float val = o[nt][r] + Oex[(wq * 32 + row) * 68 + nt * 32 + l31];
        out[((size_t)b * SEQ + srow) * E + h * D + nt * 32 + l31] = val * inv;
      }
    }
  }
}

// ---------------------------------------------------------------------------
extern "C" void kernel_launch(void* const* d_in, const int* in_sizes, int n_in,
                              void* d_out, int out_size, void* d_ws,
                              size_t ws_size, hipStream_t stream) {
  const float* rot = (const float*)d_in[0];
  const float* ent = (const float*)d_in[1];
  const float* x = (const float*)d_in[2];
  const float* wq = (const float*)d_in[3];
  const float* wk = (const float*)d_in[4];
  const float* wv = (const float*)d_in[5];
  float* out = (float*)d_out;

  const size_t NX = (size_t)BATCH * SEQ * E;  // 4M elements
  ushort* weffbT = (ushort*)d_ws;             // 3*E*E bf16 (1.5 MB)
  ushort* xh = weffbT + 3 * E * E;
  ushort* xl = xh + NX;
  ushort* qg = xl + NX;
  ushort* kg = qg + NX;
  ushort* vtg = kg + NX;

  xcast<<<dim3(NX / 1024), 256, 0, stream>>>(x, xh, xl);
  fold_tiled<<<dim3(E / 256, E / 8, 2), 256, 0, stream>>>(wq, wk, rot, ent,
                                                          weffbT);
  wv_cast<<<dim3(E * E / 1024), 256, 0, stream>>>(wv, weffbT + 2 * E * E);
  qkv_fused<<<dim3(H, BATCH * SEQ / 64), 256, 0, stream>>>(xh, xl, weffbT, qg,
                                                           kg, vtg);
  attn_mfma<<<dim3(SEQ / 128, BATCH * H), 512, 0, stream>>>(qg, kg, vtg, out);
}

// Round 6
// 241.354 us; speedup vs baseline: 1.0896x; 1.0896x over previous
//
#include <hip/hip_runtime.h>
#include <cstddef>

#define E 512
#define H 8
#define D 64
#define BATCH 2
#define SEQ 4096

typedef __attribute__((ext_vector_type(8))) short bf16x8;   // MFMA A/B frag
typedef __attribute__((ext_vector_type(4))) float f32x4;    // 16x16 C/D frag
typedef __attribute__((ext_vector_type(16))) float f32x16;  // 32x32 C/D frag
typedef __attribute__((ext_vector_type(4))) unsigned uint4v;

__device__ __forceinline__ ushort f2bf(float f) {
  unsigned u = __builtin_bit_cast(unsigned, f);
  u += 0x7fff + ((u >> 16) & 1);  // RNE
  return (ushort)(u >> 16);
}
__device__ __forceinline__ float bf2f(ushort h) {
  return __builtin_bit_cast(float, (unsigned)h << 16);
}
__device__ __forceinline__ unsigned pk_bf16(float lo, float hi) {
#if __has_builtin(__builtin_amdgcn_cvt_pk_bf16_f32)
  typedef __attribute__((ext_vector_type(2))) __bf16 bfv2;
  bfv2 r = __builtin_amdgcn_cvt_pk_bf16_f32(lo, hi);
  return __builtin_bit_cast(unsigned, r);
#else
  return (unsigned)f2bf(lo) | ((unsigned)f2bf(hi) << 16);
#endif
}
__device__ __forceinline__ float fexp2(float x) {
#if __has_builtin(__builtin_amdgcn_exp2f)
  return __builtin_amdgcn_exp2f(x);
#else
  return exp2f(x);
#endif
}
// lanes[32:63] of a  <->  lanes[0:31] of b. NON-volatile: scheduler may
// move it (we want softmax(t1) to slide under PV(t0) MFMAs).
__device__ __forceinline__ void permswap32(unsigned& a, unsigned& b) {
  asm("v_permlane32_swap_b32 %0, %1" : "+v"(a), "+v"(b));
}

// ---------------------------------------------------------------------------
// Kernel 0: cast x -> bf16 hi/lo split (xh + xl ~= x to ~16 mantissa bits)
// ---------------------------------------------------------------------------
__global__ __launch_bounds__(256) void xcast(const float* __restrict__ x,
                                             ushort* __restrict__ xh,
                                             ushort* __restrict__ xl) {
  size_t i = ((size_t)blockIdx.x * 256 + threadIdx.x) * 4;
  float4 v = *(const float4*)&x[i];
  ushort4 h, l;
  h.x = f2bf(v.x); l.x = f2bf(v.x - bf2f(h.x));
  h.y = f2bf(v.y); l.y = f2bf(v.y - bf2f(h.y));
  h.z = f2bf(v.z); l.z = f2bf(v.z - bf2f(h.z));
  h.w = f2bf(v.w); l.w = f2bf(v.w - bf2f(h.w));
  *(ushort4*)&xh[i] = h;
  *(ushort4*)&xl[i] = l;
}

// ---------------------------------------------------------------------------
// Kernel 1a: fold weights. Block = 256 k-lanes x 8 n (8 fp32 accs).
// ---------------------------------------------------------------------------
__global__ __launch_bounds__(256) void fold_tiled(
    const float* __restrict__ wq, const float* __restrict__ wk,
    const float* __restrict__ rot, const float* __restrict__ ent,
    ushort* __restrict__ weffbT) {
  const int which = blockIdx.z;
  const float* w = which ? wk : wq;
  const float* r = which ? ent : rot;
  const int k = blockIdx.x * 256 + threadIdx.x;
  const int n0 = blockIdx.y * 8;
  float acc[8] = {};
  for (int j0 = 0; j0 < E; j0 += 16) {
    float wv_[16];
#pragma unroll
    for (int u = 0; u < 16; ++u) wv_[u] = w[(size_t)(j0 + u) * E + k];
#pragma unroll
    for (int u = 0; u < 16; ++u)
#pragma unroll
      for (int t = 0; t < 8; ++t)
        acc[t] += wv_[u] * r[(size_t)(j0 + u) * E + n0 + t];
  }
#pragma unroll
  for (int t = 0; t < 8; ++t)
    weffbT[(size_t)which * E * E + (size_t)(n0 + t) * E + k] = f2bf(acc[t]);
}

// Kernel 1b: weffT[2][n][k] = bf16(wv[n][k]) — identity layout, pure cast.
__global__ __launch_bounds__(256) void wv_cast(const float* __restrict__ wv,
                                               ushort* __restrict__ dst) {
  size_t i = ((size_t)blockIdx.x * 256 + threadIdx.x) * 4;
  float4 v = *(const float4*)&wv[i];
  ushort4 o;
  o.x = f2bf(v.x); o.y = f2bf(v.y); o.z = f2bf(v.z); o.w = f2bf(v.w);
  *(ushort4*)&dst[i] = o;
}

// ---------------------------------------------------------------------------
// Kernel 2: fused QKV GEMM — REWRITTEN: 32x32x16 MFMA, 8 waves (4m x 2n),
// M=128 per block, N=192 (q|k|v heads-cols), K-step 32. Old version was
// LDS-pipe bound (4 waves each re-reading ALL B-frags: 14 ds_read_b128 per
// 24 MFMA per 16 m-rows). New: 10 reads per 12 MFMA per 32 m-rows —
// LDS traffic/m-row -29%, MFMA instrs -50%, barriers/m-row -50%.
// Layouts identical to attn's verified 32x32x16 usage:
//   A-frag: lane holds A[row=l31][c=hi*8+j] -> read Ah[(wm*32+l31)*LDQ+...]
//   B-frag: lane holds B[c][col=l31]        -> read Bs[(n-row=l31)*LDQ+...]
//   C: col=l31, row=(r&3)+8*(r>>2)+4*hi
// LDS stride 72 ushorts = 144B: conflict-free measured in attn (round 1+).
// ---------------------------------------------------------------------------
#define LDQ 72    // qkv LDS stride (ushort) = 144 B
#define LDS_S 136 // v-transpose buffer stride (ushort) = 272 B, 16B-aligned

__global__ __launch_bounds__(512, 4) void qkv_fused(
    const ushort* __restrict__ xhg, const ushort* __restrict__ xlg,
    const ushort* __restrict__ weffbT, ushort* __restrict__ qg,
    ushort* __restrict__ kg, ushort* __restrict__ vtg) {
  __shared__ ushort sm[(128 + 128 + 192) * LDQ];  // Ah | Al | B  (64.5 KB)
  ushort* Ah = sm;
  ushort* Al = sm + 128 * LDQ;
  ushort* Bs = sm + 256 * LDQ;
  ushort* vt_lds = Bs;  // epilogue reuse: 64*LDS_S = 8704 <= 192*72 = 13824

  const int head = blockIdx.x;
  const int m0 = blockIdx.y * 128;
  const int tid = threadIdx.x;
  const int wave = tid >> 6, lane = tid & 63;
  const int l31 = lane & 31, hi = lane >> 5;
  const int wm = wave & 3, wn = wave >> 2;

  // staging slots: A (128 rows x 4 chunks) = 512 -> 1/thread each for h,l.
  // B (192 rows x 4 chunks) = 768 -> slot tid + slot 512+tid (tid<256).
  const int ar = tid >> 2, ac8 = (tid & 3) * 8;
  const int b1r = tid >> 2;                    // B rows 0..127 (q|k)
  const int b2r = 128 + ((tid >> 2) & 63);     // B rows 128..191 (v); clamped

  const ushort* arow = xhg + (size_t)(m0 + ar) * E + ac8;
  const ushort* lrow = xlg + (size_t)(m0 + ar) * E + ac8;
  // B source row n -> weffbT[(n>>6)*E*E + (head*64 + (n&63))*E + k]
  const ushort* b1row =
      weffbT + (size_t)(b1r >> 6) * E * E + (size_t)(head * 64 + (b1r & 63)) * E + ac8;
  const ushort* b2row =
      weffbT + (size_t)2 * E * E + (size_t)(head * 64 + (b2r & 63)) * E + ac8;

  f32x16 acc[3];
  acc[0] = 0.f;
  acc[1] = 0.f;
  acc[2] = 0.f;

  // preload k0 = 0
  uint4 pa_h = *(const uint4*)&arow[0];
  uint4 pa_l = *(const uint4*)&lrow[0];
  uint4 pb1 = *(const uint4*)&b1row[0];
  uint4 pb2 = *(const uint4*)&b2row[0];

  const ushort* Ar = Ah + (wm * 32 + l31) * LDQ;
  const ushort* Lr = Al + (wm * 32 + l31) * LDQ;
  const ushort* Br = Bs + (wn * 96 + l31) * LDQ;

  for (int k0 = 0; k0 < E; k0 += 32) {
    __syncthreads();  // prev iter's frag reads done
    *(uint4*)&Ah[ar * LDQ + ac8] = pa_h;
    *(uint4*)&Al[ar * LDQ + ac8] = pa_l;
    *(uint4*)&Bs[b1r * LDQ + ac8] = pb1;
    if (tid < 256) *(uint4*)&Bs[b2r * LDQ + ac8] = pb2;
    __syncthreads();

    // issue NEXT tile's loads; latency hides under the MFMAs below
    const int kn = (k0 + 32 < E) ? k0 + 32 : 0;
    pa_h = *(const uint4*)&arow[kn];
    pa_l = *(const uint4*)&lrow[kn];
    pb1 = *(const uint4*)&b1row[kn];
    pb2 = *(const uint4*)&b2row[kn];

#pragma unroll
    for (int ks = 0; ks < 2; ++ks) {
      bf16x8 ah = *(const bf16x8*)&Ar[ks * 16 + hi * 8];
      bf16x8 al = *(const bf16x8*)&Lr[ks * 16 + hi * 8];
#pragma unroll
      for (int t = 0; t < 3; ++t) {
        bf16x8 bf = *(const bf16x8*)&Br[t * 32 * LDQ + ks * 16 + hi * 8];
        acc[t] =
            __builtin_amdgcn_mfma_f32_32x32x16_bf16(ah, bf, acc[t], 0, 0, 0);
        acc[t] =
            __builtin_amdgcn_mfma_f32_32x32x16_bf16(al, bf, acc[t], 0, 0, 0);
      }
    }
  }

  const int b = m0 >> 12;
  const int s_base = m0 & (SEQ - 1);
  const float QSCALE = 0.125f * 1.44269504f;  // fold 1/sqrt(D)*log2(e) into q

  // ---- q / k tiles: pair-pack (d, d+1) via shfl_xor -> u32 stores ----
#pragma unroll
  for (int t = 0; t < 3; ++t) {
    const int n0 = wn * 96 + t * 32;
    const int w = n0 >> 6;  // 0:q 1:k 2:v
    if (w != 2) {
      ushort* dst = (w == 0) ? qg : kg;
      const float sc = (w == 0) ? QSCALE : 1.0f;
      const int d = (n0 & 63) + l31;
#pragma unroll
      for (int r = 0; r < 16; ++r) {
        float v = acc[t][r] * sc;
        float vo = __shfl_xor(v, 1);
        if (!(lane & 1)) {
          int s = s_base + wm * 32 + (r & 3) + 8 * (r >> 2) + 4 * hi;
          size_t ix = ((size_t)(b * H + head) * SEQ + s) * D + d;
          *(unsigned*)&dst[ix] = pk_bf16(v, vo);
        }
      }
    }
  }

  // ---- v tiles: transpose through LDS -> coalesced vt[bh][d][s] stores ----
  __syncthreads();  // all waves done reading Bs before overlay
  if (wn == 1) {
#pragma unroll
    for (int t = 1; t < 3; ++t) {
      const int d = (t - 1) * 32 + l31;
#pragma unroll
      for (int g = 0; g < 4; ++g) {
        uint2 w2;
        w2.x = pk_bf16(acc[t][g * 4 + 0], acc[t][g * 4 + 1]);
        w2.y = pk_bf16(acc[t][g * 4 + 2], acc[t][g * 4 + 3]);
        int s = wm * 32 + 8 * g + 4 * hi;
        *(uint2*)&vt_lds[d * LDS_S + s] = w2;
      }
    }
  }
  __syncthreads();
  {
    int vr = tid >> 3, vs = (tid & 7) * 16;  // d-row, 16-col s chunk
    uint4 c0 = *(const uint4*)&vt_lds[vr * LDS_S + vs];
    uint4 c1 = *(const uint4*)&vt_lds[vr * LDS_S + vs + 8];
    size_t vo = ((size_t)(b * H + head) * D + vr) * SEQ + s_base + vs;
    *(uint4*)&vtg[vo] = c0;
    *(uint4*)&vtg[vo + 8] = c1;
  }
}

// ---------------------------------------------------------------------------
// Kernel 3: flash attention (UNCHANGED from round 5 — verified at 94 µs).
// Round-4 ILP body (interleaved QK chains, pipelined sm/PV, P in registers)
// + round-1 in-block K-split (8 waves = 2 k-groups x 4 q-waves).
// ---------------------------------------------------------------------------
#define LDK 72  // padded stride (bf16): 144B, 16B-aligned

__global__ __launch_bounds__(512, 4) void attn_mfma(
    const ushort* __restrict__ qg, const ushort* __restrict__ kg,
    const ushort* __restrict__ vtg, float* __restrict__ out) {
  __shared__ ushort sm[4 * 64 * LDK + 256];  // Ks[2] | Vs[2] | lex
  ushort* Ks0 = sm;
  ushort* Vs0 = sm + 2 * 64 * LDK;
  float* lex = (float*)(sm + 4 * 64 * LDK);  // 128 floats

  const int qt = blockIdx.x;  // 0..31 (128 q-rows each)
  const int bh = blockIdx.y;
  const int tid = threadIdx.x;
  const int wave = tid >> 6;  // 0..7
  const int grp = wave >> 2, wq = wave & 3;
  const int lane = tid & 63;
  const int l31 = lane & 31, hi = lane >> 5;
  const int gtid = tid & 255;  // tid within group

  const ushort* qp = qg + (size_t)bh * SEQ * D;
  const ushort* kp = kg + (size_t)bh * SEQ * D;
  const ushort* vp = vtg + (size_t)bh * D * SEQ;
  ushort* Ksg = Ks0 + grp * 64 * LDK;
  ushort* Vsg = Vs0 + grp * 64 * LDK;

  const int qrow0 = qt * 128 + wq * 32;
  // Q as B-operand: qf[ds] lane holds Q[qrow0+l31][ds*16 + hi*8 + j]
  bf16x8 qf[4];
#pragma unroll
  for (int ds = 0; ds < 4; ++ds)
    qf[ds] =
        *(const bf16x8*)&qp[(size_t)(qrow0 + l31) * D + ds * 16 + hi * 8];

  f32x16 o[2];
  o[0] = 0.f;
  o[1] = 0.f;
  float l_r = 0.f;  // per-lane partial row-sum for q = qrow0 + l31

  // staging: each group's 256 threads cover its 64x64 K and V tiles
  const int r0 = gtid >> 3, c0 = (gtid & 7) * 8;  // r0 in 0..31
  const int r1 = 32 + r0;

  // preload tile it=0 (kt = grp)
  uint4 pk0 = *(const uint4*)&kp[(size_t)(grp * 64 + r0) * D + c0];
  uint4 pk1 = *(const uint4*)&kp[(size_t)(grp * 64 + r1) * D + c0];
  uint4 pv0 = *(const uint4*)&vp[(size_t)r0 * SEQ + grp * 64 + c0];
  uint4 pv1 = *(const uint4*)&vp[(size_t)r1 * SEQ + grp * 64 + c0];

  for (int it = 0; it < SEQ / 128; ++it) {
    __syncthreads();  // prev iter's frag reads done (both groups)
    *(uint4*)&Ksg[r0 * LDK + c0] = pk0;
    *(uint4*)&Ksg[r1 * LDK + c0] = pk1;
    *(uint4*)&Vsg[r0 * LDK + c0] = pv0;
    *(uint4*)&Vsg[r1 * LDK + c0] = pv1;
    __syncthreads();

    // issue NEXT tile's loads; latency hides under this tile's compute
    {
      const int itn = (it + 1 < SEQ / 128) ? it + 1 : it;
      const int ktn = itn * 2 + grp;
      const ushort* ksrc = kp + (size_t)ktn * 64 * D;
      pk0 = *(const uint4*)&ksrc[r0 * D + c0];
      pk1 = *(const uint4*)&ksrc[r1 * D + c0];
      pv0 = *(const uint4*)&vp[(size_t)r0 * SEQ + ktn * 64 + c0];
      pv1 = *(const uint4*)&vp[(size_t)r1 * SEQ + ktn * 64 + c0];
    }

    __builtin_amdgcn_s_setprio(1);
    // ---- QK for BOTH 32-k subtiles, chains interleaved ----
    f32x16 st0 = 0.f, st1 = 0.f;
#pragma unroll
    for (int ds = 0; ds < 4; ++ds) {
      bf16x8 kf0 = *(const bf16x8*)&Ksg[(l31)*LDK + ds * 16 + hi * 8];
      bf16x8 kf1 = *(const bf16x8*)&Ksg[(32 + l31) * LDK + ds * 16 + hi * 8];
      st0 = __builtin_amdgcn_mfma_f32_32x32x16_bf16(kf0, qf[ds], st0, 0, 0, 0);
      st1 = __builtin_amdgcn_mfma_f32_32x32x16_bf16(kf1, qf[ds], st1, 0, 0, 0);
    }

    // ---- t = 0: softmax + P-frag build + PV ----
    bf16x8 pf00, pf01;
    {
      float pv[16];
#pragma unroll
      for (int r = 0; r < 16; ++r) pv[r] = fexp2(st0[r]);
      float s01 = (pv[0] + pv[1]) + (pv[2] + pv[3]);
      float s23 = (pv[4] + pv[5]) + (pv[6] + pv[7]);
      float s45 = (pv[8] + pv[9]) + (pv[10] + pv[11]);
      float s67 = (pv[12] + pv[13]) + (pv[14] + pv[15]);
      l_r += (s01 + s23) + (s45 + s67);
      unsigned w0[4], w1[4];
#pragma unroll
      for (int j = 0; j < 2; ++j) {
        {
          unsigned c0w = pk_bf16(pv[2 * j + 0], pv[2 * j + 1]);
          unsigned c1w = pk_bf16(pv[2 * j + 4], pv[2 * j + 5]);
          permswap32(c0w, c1w);
          w0[j] = c0w;
          w0[2 + j] = c1w;
        }
        {
          unsigned c0w = pk_bf16(pv[2 * j + 8], pv[2 * j + 9]);
          unsigned c1w = pk_bf16(pv[2 * j + 12], pv[2 * j + 13]);
          permswap32(c0w, c1w);
          w1[j] = c0w;
          w1[2 + j] = c1w;
        }
      }
      pf00 = __builtin_bit_cast(bf16x8, (uint4v){w0[0], w0[1], w0[2], w0[3]});
      pf01 = __builtin_bit_cast(bf16x8, (uint4v){w1[0], w1[1], w1[2], w1[3]});
    }
#pragma unroll
    for (int nt = 0; nt < 2; ++nt) {
      bf16x8 vf0 = *(const bf16x8*)&Vsg[(nt * 32 + l31) * LDK + hi * 8];
      o[nt] =
          __builtin_amdgcn_mfma_f32_32x32x16_bf16(pf00, vf0, o[nt], 0, 0, 0);
      bf16x8 vf1 = *(const bf16x8*)&Vsg[(nt * 32 + l31) * LDK + 16 + hi * 8];
      o[nt] =
          __builtin_amdgcn_mfma_f32_32x32x16_bf16(pf01, vf1, o[nt], 0, 0, 0);
    }

    // ---- t = 1: softmax (scheduler may overlap with PV(t0)) + PV ----
    bf16x8 pf10, pf11;
    {
      float pv[16];
#pragma unroll
      for (int r = 0; r < 16; ++r) pv[r] = fexp2(st1[r]);
      float s01 = (pv[0] + pv[1]) + (pv[2] + pv[3]);
      float s23 = (pv[4] + pv[5]) + (pv[6] + pv[7]);
      float s45 = (pv[8] + pv[9]) + (pv[10] + pv[11]);
      float s67 = (pv[12] + pv[13]) + (pv[14] + pv[15]);
      l_r += (s01 + s23) + (s45 + s67);
      unsigned w0[4], w1[4];
#pragma unroll
      for (int j = 0; j < 2; ++j) {
        {
          unsigned c0w = pk_bf16(pv[2 * j + 0], pv[2 * j + 1]);
          unsigned c1w = pk_bf16(pv[2 * j + 4], pv[2 * j + 5]);
          permswap32(c0w, c1w);
          w0[j] = c0w;
          w0[2 + j] = c1w;
        }
        {
          unsigned c0w = pk_bf16(pv[2 * j + 8], pv[2 * j + 9]);
          unsigned c1w = pk_bf16(pv[2 * j + 12], pv[2 * j + 13]);
          permswap32(c0w, c1w);
          w1[j] = c0w;
          w1[2 + j] = c1w;
        }
      }
      pf10 = __builtin_bit_cast(bf16x8, (uint4v){w0[0], w0[1], w0[2], w0[3]});
      pf11 = __builtin_bit_cast(bf16x8, (uint4v){w1[0], w1[1], w1[2], w1[3]});
    }
#pragma unroll
    for (int nt = 0; nt < 2; ++nt) {
      bf16x8 vf0 = *(const bf16x8*)&Vsg[(nt * 32 + l31) * LDK + 32 + hi * 8];
      o[nt] =
          __builtin_amdgcn_mfma_f32_32x32x16_bf16(pf10, vf0, o[nt], 0, 0, 0);
      bf16x8 vf1 = *(const bf16x8*)&Vsg[(nt * 32 + l31) * LDK + 48 + hi * 8];
      o[nt] =
          __builtin_amdgcn_mfma_f32_32x32x16_bf16(pf11, vf1, o[nt], 0, 0, 0);
    }
    __builtin_amdgcn_s_setprio(0);
  }

  // ---- combine the two K-halves (additive: no max bookkeeping) ----
  __syncthreads();  // all waves done with Ks/Vs before Oex overlay
  float lg = l_r + __shfl_xor(l_r, 32);  // lanes l/l+32 cover all 32 k-rows
  float* Oex = (float*)sm;               // [128 q][64 d], stride 68 floats
  if (grp == 1) {
#pragma unroll
    for (int nt = 0; nt < 2; ++nt)
#pragma unroll
      for (int r = 0; r < 16; ++r) {
        int row = (r & 3) + 8 * (r >> 2) + 4 * hi;
        Oex[(wq * 32 + row) * 68 + nt * 32 + l31] = o[nt][r];
      }
    if (lane < 32) lex[wq * 32 + l31] = lg;
  }
  __syncthreads();
  if (grp == 0) {
    float linv = 1.f / (lg + lex[wq * 32 + l31]);
    const int b = bh >> 3, h = bh & 7;
#pragma unroll
    for (int r = 0; r < 16; ++r) {
      int row = (r & 3) + 8 * (r >> 2) + 4 * hi;
      float inv = __shfl(linv, row);  // lane `row` owns q = qrow0 + row
      int srow = qt * 128 + wq * 32 + row;
#pragma unroll
      for (int nt = 0; nt < 2; ++nt) {
        float val = o[nt][r] + Oex[(wq * 32 + row) * 68 + nt * 32 + l31];
        out[((size_t)b * SEQ + srow) * E + h * D + nt * 32 + l31] = val * inv;
      }
    }
  }
}

// ---------------------------------------------------------------------------
extern "C" void kernel_launch(void* const* d_in, const int* in_sizes, int n_in,
                              void* d_out, int out_size, void* d_ws,
                              size_t ws_size, hipStream_t stream) {
  const float* rot = (const float*)d_in[0];
  const float* ent = (const float*)d_in[1];
  const float* x = (const float*)d_in[2];
  const float* wq = (const float*)d_in[3];
  const float* wk = (const float*)d_in[4];
  const float* wv = (const float*)d_in[5];
  float* out = (float*)d_out;

  const size_t NX = (size_t)BATCH * SEQ * E;  // 4M elements
  ushort* weffbT = (ushort*)d_ws;             // 3*E*E bf16 (1.5 MB)
  ushort* xh = weffbT + 3 * E * E;
  ushort* xl = xh + NX;
  ushort* qg = xl + NX;
  ushort* kg = qg + NX;
  ushort* vtg = kg + NX;

  xcast<<<dim3(NX / 1024), 256, 0, stream>>>(x, xh, xl);
  fold_tiled<<<dim3(E / 256, E / 8, 2), 256, 0, stream>>>(wq, wk, rot, ent,
                                                          weffbT);
  wv_cast<<<dim3(E * E / 1024), 256, 0, stream>>>(wv, weffbT + 2 * E * E);
  qkv_fused<<<dim3(H, BATCH * SEQ / 128), 512, 0, stream>>>(xh, xl, weffbT, qg,
                                                            kg, vtg);
  attn_mfma<<<dim3(SEQ / 128, BATCH * H), 512, 0, stream>>>(qg, kg, vtg, out);
}

// Round 7
// 232.921 us; speedup vs baseline: 1.1290x; 1.0362x over previous
//
#include <hip/hip_runtime.h>
#include <cstddef>

#define E 512
#define H 8
#define D 64
#define BATCH 2
#define SEQ 4096

typedef __attribute__((ext_vector_type(8))) short bf16x8;   // MFMA A/B frag
typedef __attribute__((ext_vector_type(4))) float f32x4;    // 16x16 C/D frag
typedef __attribute__((ext_vector_type(16))) float f32x16;  // 32x32 C/D frag
typedef __attribute__((ext_vector_type(4))) unsigned uint4v;

__device__ __forceinline__ ushort f2bf(float f) {
  unsigned u = __builtin_bit_cast(unsigned, f);
  u += 0x7fff + ((u >> 16) & 1);  // RNE
  return (ushort)(u >> 16);
}
__device__ __forceinline__ float bf2f(ushort h) {
  return __builtin_bit_cast(float, (unsigned)h << 16);
}
__device__ __forceinline__ unsigned pk_bf16(float lo, float hi) {
#if __has_builtin(__builtin_amdgcn_cvt_pk_bf16_f32)
  typedef __attribute__((ext_vector_type(2))) __bf16 bfv2;
  bfv2 r = __builtin_amdgcn_cvt_pk_bf16_f32(lo, hi);
  return __builtin_bit_cast(unsigned, r);
#else
  return (unsigned)f2bf(lo) | ((unsigned)f2bf(hi) << 16);
#endif
}
__device__ __forceinline__ float fexp2(float x) {
#if __has_builtin(__builtin_amdgcn_exp2f)
  return __builtin_amdgcn_exp2f(x);
#else
  return exp2f(x);
#endif
}
// lanes[32:63] of a  <->  lanes[0:31] of b. NON-volatile: scheduler may
// move it (we want softmax(t1) to slide under PV(t0) MFMAs).
__device__ __forceinline__ void permswap32(unsigned& a, unsigned& b) {
  asm("v_permlane32_swap_b32 %0, %1" : "+v"(a), "+v"(b));
}

// ---------------------------------------------------------------------------
// Kernel 0: cast x -> bf16 hi/lo split (xh + xl ~= x to ~16 mantissa bits)
// ---------------------------------------------------------------------------
__global__ __launch_bounds__(256) void xcast(const float* __restrict__ x,
                                             ushort* __restrict__ xh,
                                             ushort* __restrict__ xl) {
  size_t i = ((size_t)blockIdx.x * 256 + threadIdx.x) * 4;
  float4 v = *(const float4*)&x[i];
  ushort4 h, l;
  h.x = f2bf(v.x); l.x = f2bf(v.x - bf2f(h.x));
  h.y = f2bf(v.y); l.y = f2bf(v.y - bf2f(h.y));
  h.z = f2bf(v.z); l.z = f2bf(v.z - bf2f(h.z));
  h.w = f2bf(v.w); l.w = f2bf(v.w - bf2f(h.w));
  *(ushort4*)&xh[i] = h;
  *(ushort4*)&xl[i] = l;
}

// ---------------------------------------------------------------------------
// Kernel 1a: fold weights. Block = 256 k-lanes x 8 n (8 fp32 accs).
// ---------------------------------------------------------------------------
__global__ __launch_bounds__(256) void fold_tiled(
    const float* __restrict__ wq, const float* __restrict__ wk,
    const float* __restrict__ rot, const float* __restrict__ ent,
    ushort* __restrict__ weffbT) {
  const int which = blockIdx.z;
  const float* w = which ? wk : wq;
  const float* r = which ? ent : rot;
  const int k = blockIdx.x * 256 + threadIdx.x;
  const int n0 = blockIdx.y * 8;
  float acc[8] = {};
  for (int j0 = 0; j0 < E; j0 += 16) {
    float wv_[16];
#pragma unroll
    for (int u = 0; u < 16; ++u) wv_[u] = w[(size_t)(j0 + u) * E + k];
#pragma unroll
    for (int u = 0; u < 16; ++u)
#pragma unroll
      for (int t = 0; t < 8; ++t)
        acc[t] += wv_[u] * r[(size_t)(j0 + u) * E + n0 + t];
  }
#pragma unroll
  for (int t = 0; t < 8; ++t)
    weffbT[(size_t)which * E * E + (size_t)(n0 + t) * E + k] = f2bf(acc[t]);
}

// Kernel 1b: weffT[2][n][k] = bf16(wv[n][k]) — identity layout, pure cast.
__global__ __launch_bounds__(256) void wv_cast(const float* __restrict__ wv,
                                               ushort* __restrict__ dst) {
  size_t i = ((size_t)blockIdx.x * 256 + threadIdx.x) * 4;
  float4 v = *(const float4*)&wv[i];
  ushort4 o;
  o.x = f2bf(v.x); o.y = f2bf(v.y); o.z = f2bf(v.z); o.w = f2bf(v.w);
  *(ushort4*)&dst[i] = o;
}

// ---------------------------------------------------------------------------
// Kernel 2: fused QKV GEMM, 32x32x16 MFMA, 8 waves (4m x 2n), M=128/block.
// NEW this round: XCD-aware block swizzle. Old dispatch put the 8 head-
// blocks sharing one 256KB A-tile on 8 DIFFERENT XCDs (private L2s) ->
// A (16MB hi+lo) fetched ~8x from HBM. Swizzle new=(lin%8)*64+lin/8 gives
// XCD r the m-blocks [8r,8r+8) x all heads: per-XCD A set 2MB, B 1.5MB,
// both L2-resident; staged loads become L2 hits (~200cyc vs ~900).
// Also: pb2 load now guarded to tid<256 (was loaded by all, stored by half).
// ---------------------------------------------------------------------------
#define LDQ 72    // qkv LDS stride (ushort) = 144 B
#define LDS_S 136 // v-transpose buffer stride (ushort) = 272 B, 16B-aligned

__global__ __launch_bounds__(512, 4) void qkv_fused(
    const ushort* __restrict__ xhg, const ushort* __restrict__ xlg,
    const ushort* __restrict__ weffbT, ushort* __restrict__ qg,
    ushort* __restrict__ kg, ushort* __restrict__ vtg) {
  __shared__ ushort sm[(128 + 128 + 192) * LDQ];  // Ah | Al | B  (64.5 KB)
  ushort* Ah = sm;
  ushort* Al = sm + 128 * LDQ;
  ushort* Bs = sm + 256 * LDQ;
  ushort* vt_lds = Bs;  // epilogue reuse: 64*LDS_S = 8704 <= 192*72 = 13824

  // XCD swizzle: lin%8 tracks HW round-robin XCD assignment; give each XCD
  // a contiguous chunk of m-blocks (all heads) so A-tiles stay in its L2.
  const int lin = blockIdx.y * 8 + blockIdx.x;  // 0..511
  const int nl = (lin & 7) * 64 + (lin >> 3);
  const int head = nl & 7;
  const int m0 = (nl >> 3) * 128;

  const int tid = threadIdx.x;
  const int wave = tid >> 6, lane = tid & 63;
  const int l31 = lane & 31, hi = lane >> 5;
  const int wm = wave & 3, wn = wave >> 2;

  // staging slots: A (128 rows x 4 chunks) = 512 -> 1/thread each for h,l.
  // B (192 rows x 4 chunks) = 768 -> slot tid + slot 512+tid (tid<256).
  const int ar = tid >> 2, ac8 = (tid & 3) * 8;
  const int b1r = tid >> 2;                    // B rows 0..127 (q|k)
  const int b2r = 128 + ((tid >> 2) & 63);     // B rows 128..191 (v)

  const ushort* arow = xhg + (size_t)(m0 + ar) * E + ac8;
  const ushort* lrow = xlg + (size_t)(m0 + ar) * E + ac8;
  // B source row n -> weffbT[(n>>6)*E*E + (head*64 + (n&63))*E + k]
  const ushort* b1row =
      weffbT + (size_t)(b1r >> 6) * E * E + (size_t)(head * 64 + (b1r & 63)) * E + ac8;
  const ushort* b2row =
      weffbT + (size_t)2 * E * E + (size_t)(head * 64 + (b2r & 63)) * E + ac8;

  f32x16 acc[3];
  acc[0] = 0.f;
  acc[1] = 0.f;
  acc[2] = 0.f;

  // preload k0 = 0
  uint4 pa_h = *(const uint4*)&arow[0];
  uint4 pa_l = *(const uint4*)&lrow[0];
  uint4 pb1 = *(const uint4*)&b1row[0];
  uint4 pb2 = (tid < 256) ? *(const uint4*)&b2row[0] : uint4{0, 0, 0, 0};

  const ushort* Ar = Ah + (wm * 32 + l31) * LDQ;
  const ushort* Lr = Al + (wm * 32 + l31) * LDQ;
  const ushort* Br = Bs + (wn * 96 + l31) * LDQ;

  for (int k0 = 0; k0 < E; k0 += 32) {
    __syncthreads();  // prev iter's frag reads done
    *(uint4*)&Ah[ar * LDQ + ac8] = pa_h;
    *(uint4*)&Al[ar * LDQ + ac8] = pa_l;
    *(uint4*)&Bs[b1r * LDQ + ac8] = pb1;
    if (tid < 256) *(uint4*)&Bs[b2r * LDQ + ac8] = pb2;
    __syncthreads();

    // issue NEXT tile's loads; latency hides under the MFMAs below
    const int kn = (k0 + 32 < E) ? k0 + 32 : 0;
    pa_h = *(const uint4*)&arow[kn];
    pa_l = *(const uint4*)&lrow[kn];
    pb1 = *(const uint4*)&b1row[kn];
    if (tid < 256) pb2 = *(const uint4*)&b2row[kn];

#pragma unroll
    for (int ks = 0; ks < 2; ++ks) {
      bf16x8 ah = *(const bf16x8*)&Ar[ks * 16 + hi * 8];
      bf16x8 al = *(const bf16x8*)&Lr[ks * 16 + hi * 8];
#pragma unroll
      for (int t = 0; t < 3; ++t) {
        bf16x8 bf = *(const bf16x8*)&Br[t * 32 * LDQ + ks * 16 + hi * 8];
        acc[t] =
            __builtin_amdgcn_mfma_f32_32x32x16_bf16(ah, bf, acc[t], 0, 0, 0);
        acc[t] =
            __builtin_amdgcn_mfma_f32_32x32x16_bf16(al, bf, acc[t], 0, 0, 0);
      }
    }
  }

  const int b = m0 >> 12;
  const int s_base = m0 & (SEQ - 1);
  const float QSCALE = 0.125f * 1.44269504f;  // fold 1/sqrt(D)*log2(e) into q

  // ---- q / k tiles: pair-pack (d, d+1) via shfl_xor -> u32 stores ----
#pragma unroll
  for (int t = 0; t < 3; ++t) {
    const int n0 = wn * 96 + t * 32;
    const int w = n0 >> 6;  // 0:q 1:k 2:v
    if (w != 2) {
      ushort* dst = (w == 0) ? qg : kg;
      const float sc = (w == 0) ? QSCALE : 1.0f;
      const int d = (n0 & 63) + l31;
#pragma unroll
      for (int r = 0; r < 16; ++r) {
        float v = acc[t][r] * sc;
        float vo = __shfl_xor(v, 1);
        if (!(lane & 1)) {
          int s = s_base + wm * 32 + (r & 3) + 8 * (r >> 2) + 4 * hi;
          size_t ix = ((size_t)(b * H + head) * SEQ + s) * D + d;
          *(unsigned*)&dst[ix] = pk_bf16(v, vo);
        }
      }
    }
  }

  // ---- v tiles: transpose through LDS -> coalesced vt[bh][d][s] stores ----
  __syncthreads();  // all waves done reading Bs before overlay
  if (wn == 1) {
#pragma unroll
    for (int t = 1; t < 3; ++t) {
      const int d = (t - 1) * 32 + l31;
#pragma unroll
      for (int g = 0; g < 4; ++g) {
        uint2 w2;
        w2.x = pk_bf16(acc[t][g * 4 + 0], acc[t][g * 4 + 1]);
        w2.y = pk_bf16(acc[t][g * 4 + 2], acc[t][g * 4 + 3]);
        int s = wm * 32 + 8 * g + 4 * hi;
        *(uint2*)&vt_lds[d * LDS_S + s] = w2;
      }
    }
  }
  __syncthreads();
  {
    int vr = tid >> 3, vs = (tid & 7) * 16;  // d-row, 16-col s chunk
    uint4 c0 = *(const uint4*)&vt_lds[vr * LDS_S + vs];
    uint4 c1 = *(const uint4*)&vt_lds[vr * LDS_S + vs + 8];
    size_t vo = ((size_t)(b * H + head) * D + vr) * SEQ + s_base + vs;
    *(uint4*)&vtg[vo] = c0;
    *(uint4*)&vtg[vo + 8] = c1;
  }
}

// ---------------------------------------------------------------------------
// Kernel 3: flash attention (round-5 body, verified at 94 µs) + NEW:
// XCD-aware block swizzle. Old dispatch spread each bh's 32 q-tiles over
// all 8 XCDs -> every XCD L2 fetched every bh's K/V (FETCH 70MB vs 24
// ideal). Swizzle gives XCD r the pair bh in {2r,2r+1} (all qt): per-XCD
// K/V set 2MB -> L2-resident, staged loads become L2 hits.
// ---------------------------------------------------------------------------
#define LDK 72  // padded stride (bf16): 144B, 16B-aligned

__global__ __launch_bounds__(512, 4) void attn_mfma(
    const ushort* __restrict__ qg, const ushort* __restrict__ kg,
    const ushort* __restrict__ vtg, float* __restrict__ out) {
  __shared__ ushort sm[4 * 64 * LDK + 256];  // Ks[2] | Vs[2] | lex
  ushort* Ks0 = sm;
  ushort* Vs0 = sm + 2 * 64 * LDK;
  float* lex = (float*)(sm + 4 * 64 * LDK);  // 128 floats

  // XCD swizzle: each XCD gets 2 full bh (64 consecutive new-ids).
  const int lin = blockIdx.y * gridDim.x + blockIdx.x;  // 0..511
  const int nl = (lin & 7) * 64 + (lin >> 3);
  const int qt = nl & 31;   // 0..31 (128 q-rows each)
  const int bh = nl >> 5;   // 0..15

  const int tid = threadIdx.x;
  const int wave = tid >> 6;  // 0..7
  const int grp = wave >> 2, wq = wave & 3;
  const int lane = tid & 63;
  const int l31 = lane & 31, hi = lane >> 5;
  const int gtid = tid & 255;  // tid within group

  const ushort* qp = qg + (size_t)bh * SEQ * D;
  const ushort* kp = kg + (size_t)bh * SEQ * D;
  const ushort* vp = vtg + (size_t)bh * D * SEQ;
  ushort* Ksg = Ks0 + grp * 64 * LDK;
  ushort* Vsg = Vs0 + grp * 64 * LDK;

  const int qrow0 = qt * 128 + wq * 32;
  // Q as B-operand: qf[ds] lane holds Q[qrow0+l31][ds*16 + hi*8 + j]
  bf16x8 qf[4];
#pragma unroll
  for (int ds = 0; ds < 4; ++ds)
    qf[ds] =
        *(const bf16x8*)&qp[(size_t)(qrow0 + l31) * D + ds * 16 + hi * 8];

  f32x16 o[2];
  o[0] = 0.f;
  o[1] = 0.f;
  float l_r = 0.f;  // per-lane partial row-sum for q = qrow0 + l31

  // staging: each group's 256 threads cover its 64x64 K and V tiles
  const int r0 = gtid >> 3, c0 = (gtid & 7) * 8;  // r0 in 0..31
  const int r1 = 32 + r0;

  // preload tile it=0 (kt = grp)
  uint4 pk0 = *(const uint4*)&kp[(size_t)(grp * 64 + r0) * D + c0];
  uint4 pk1 = *(const uint4*)&kp[(size_t)(grp * 64 + r1) * D + c0];
  uint4 pv0 = *(const uint4*)&vp[(size_t)r0 * SEQ + grp * 64 + c0];
  uint4 pv1 = *(const uint4*)&vp[(size_t)r1 * SEQ + grp * 64 + c0];

  for (int it = 0; it < SEQ / 128; ++it) {
    __syncthreads();  // prev iter's frag reads done (both groups)
    *(uint4*)&Ksg[r0 * LDK + c0] = pk0;
    *(uint4*)&Ksg[r1 * LDK + c0] = pk1;
    *(uint4*)&Vsg[r0 * LDK + c0] = pv0;
    *(uint4*)&Vsg[r1 * LDK + c0] = pv1;
    __syncthreads();

    // issue NEXT tile's loads; latency hides under this tile's compute
    {
      const int itn = (it + 1 < SEQ / 128) ? it + 1 : it;
      const int ktn = itn * 2 + grp;
      const ushort* ksrc = kp + (size_t)ktn * 64 * D;
      pk0 = *(const uint4*)&ksrc[r0 * D + c0];
      pk1 = *(const uint4*)&ksrc[r1 * D + c0];
      pv0 = *(const uint4*)&vp[(size_t)r0 * SEQ + ktn * 64 + c0];
      pv1 = *(const uint4*)&vp[(size_t)r1 * SEQ + ktn * 64 + c0];
    }

    __builtin_amdgcn_s_setprio(1);
    // ---- QK for BOTH 32-k subtiles, chains interleaved ----
    f32x16 st0 = 0.f, st1 = 0.f;
#pragma unroll
    for (int ds = 0; ds < 4; ++ds) {
      bf16x8 kf0 = *(const bf16x8*)&Ksg[(l31)*LDK + ds * 16 + hi * 8];
      bf16x8 kf1 = *(const bf16x8*)&Ksg[(32 + l31) * LDK + ds * 16 + hi * 8];
      st0 = __builtin_amdgcn_mfma_f32_32x32x16_bf16(kf0, qf[ds], st0, 0, 0, 0);
      st1 = __builtin_amdgcn_mfma_f32_32x32x16_bf16(kf1, qf[ds], st1, 0, 0, 0);
    }

    // ---- t = 0: softmax + P-frag build + PV ----
    bf16x8 pf00, pf01;
    {
      float pv[16];
#pragma unroll
      for (int r = 0; r < 16; ++r) pv[r] = fexp2(st0[r]);
      float s01 = (pv[0] + pv[1]) + (pv[2] + pv[3]);
      float s23 = (pv[4] + pv[5]) + (pv[6] + pv[7]);
      float s45 = (pv[8] + pv[9]) + (pv[10] + pv[11]);
      float s67 = (pv[12] + pv[13]) + (pv[14] + pv[15]);
      l_r += (s01 + s23) + (s45 + s67);
      unsigned w0[4], w1[4];
#pragma unroll
      for (int j = 0; j < 2; ++j) {
        {
          unsigned c0w = pk_bf16(pv[2 * j + 0], pv[2 * j + 1]);
          unsigned c1w = pk_bf16(pv[2 * j + 4], pv[2 * j + 5]);
          permswap32(c0w, c1w);
          w0[j] = c0w;
          w0[2 + j] = c1w;
        }
        {
          unsigned c0w = pk_bf16(pv[2 * j + 8], pv[2 * j + 9]);
          unsigned c1w = pk_bf16(pv[2 * j + 12], pv[2 * j + 13]);
          permswap32(c0w, c1w);
          w1[j] = c0w;
          w1[2 + j] = c1w;
        }
      }
      pf00 = __builtin_bit_cast(bf16x8, (uint4v){w0[0], w0[1], w0[2], w0[3]});
      pf01 = __builtin_bit_cast(bf16x8, (uint4v){w1[0], w1[1], w1[2], w1[3]});
    }
#pragma unroll
    for (int nt = 0; nt < 2; ++nt) {
      bf16x8 vf0 = *(const bf16x8*)&Vsg[(nt * 32 + l31) * LDK + hi * 8];
      o[nt] =
          __builtin_amdgcn_mfma_f32_32x32x16_bf16(pf00, vf0, o[nt], 0, 0, 0);
      bf16x8 vf1 = *(const bf16x8*)&Vsg[(nt * 32 + l31) * LDK + 16 + hi * 8];
      o[nt] =
          __builtin_amdgcn_mfma_f32_32x32x16_bf16(pf01, vf1, o[nt], 0, 0, 0);
    }

    // ---- t = 1: softmax (scheduler may overlap with PV(t0)) + PV ----
    bf16x8 pf10, pf11;
    {
      float pv[16];
#pragma unroll
      for (int r = 0; r < 16; ++r) pv[r] = fexp2(st1[r]);
      float s01 = (pv[0] + pv[1]) + (pv[2] + pv[3]);
      float s23 = (pv[4] + pv[5]) + (pv[6] + pv[7]);
      float s45 = (pv[8] + pv[9]) + (pv[10] + pv[11]);
      float s67 = (pv[12] + pv[13]) + (pv[14] + pv[15]);
      l_r += (s01 + s23) + (s45 + s67);
      unsigned w0[4], w1[4];
#pragma unroll
      for (int j = 0; j < 2; ++j) {
        {
          unsigned c0w = pk_bf16(pv[2 * j + 0], pv[2 * j + 1]);
          unsigned c1w = pk_bf16(pv[2 * j + 4], pv[2 * j + 5]);
          permswap32(c0w, c1w);
          w0[j] = c0w;
          w0[2 + j] = c1w;
        }
        {
          unsigned c0w = pk_bf16(pv[2 * j + 8], pv[2 * j + 9]);
          unsigned c1w = pk_bf16(pv[2 * j + 12], pv[2 * j + 13]);
          permswap32(c0w, c1w);
          w1[j] = c0w;
          w1[2 + j] = c1w;
        }
      }
      pf10 = __builtin_bit_cast(bf16x8, (uint4v){w0[0], w0[1], w0[2], w0[3]});
      pf11 = __builtin_bit_cast(bf16x8, (uint4v){w1[0], w1[1], w1[2], w1[3]});
    }
#pragma unroll
    for (int nt = 0; nt < 2; ++nt) {
      bf16x8 vf0 = *(const bf16x8*)&Vsg[(nt * 32 + l31) * LDK + 32 + hi * 8];
      o[nt] =
          __builtin_amdgcn_mfma_f32_32x32x16_bf16(pf10, vf0, o[nt], 0, 0, 0);
      bf16x8 vf1 = *(const bf16x8*)&Vsg[(nt * 32 + l31) * LDK + 48 + hi * 8];
      o[nt] =
          __builtin_amdgcn_mfma_f32_32x32x16_bf16(pf11, vf1, o[nt], 0, 0, 0);
    }
    __builtin_amdgcn_s_setprio(0);
  }

  // ---- combine the two K-halves (additive: no max bookkeeping) ----
  __syncthreads();  // all waves done with Ks/Vs before Oex overlay
  float lg = l_r + __shfl_xor(l_r, 32);  // lanes l/l+32 cover all 32 k-rows
  float* Oex = (float*)sm;               // [128 q][64 d], stride 68 floats
  if (grp == 1) {
#pragma unroll
    for (int nt = 0; nt < 2; ++nt)
#pragma unroll
      for (int r = 0; r < 16; ++r) {
        int row = (r & 3) + 8 * (r >> 2) + 4 * hi;
        Oex[(wq * 32 + row) * 68 + nt * 32 + l31] = o[nt][r];
      }
    if (lane < 32) lex[wq * 32 + l31] = lg;
  }
  __syncthreads();
  if (grp == 0) {
    float linv = 1.f / (lg + lex[wq * 32 + l31]);
    const int b = bh >> 3, h = bh & 7;
#pragma unroll
    for (int r = 0; r < 16; ++r) {
      int row = (r & 3) + 8 * (r >> 2) + 4 * hi;
      float inv = __shfl(linv, row);  // lane `row` owns q = qrow0 + row
      int srow = qt * 128 + wq * 32 + row;
#pragma unroll
      for (int nt = 0; nt < 2; ++nt) {
        float val = o[nt][r] + Oex[(wq * 32 + row) * 68 + nt * 32 + l31];
        out[((size_t)b * SEQ + srow) * E + h * D + nt * 32 + l31] = val * inv;
      }
    }
  }
}

// ---------------------------------------------------------------------------
extern "C" void kernel_launch(void* const* d_in, const int* in_sizes, int n_in,
                              void* d_out, int out_size, void* d_ws,
                              size_t ws_size, hipStream_t stream) {
  const float* rot = (const float*)d_in[0];
  const float* ent = (const float*)d_in[1];
  const float* x = (const float*)d_in[2];
  const float* wq = (const float*)d_in[3];
  const float* wk = (const float*)d_in[4];
  const float* wv = (const float*)d_in[5];
  float* out = (float*)d_out;

  const size_t NX = (size_t)BATCH * SEQ * E;  // 4M elements
  ushort* weffbT = (ushort*)d_ws;             // 3*E*E bf16 (1.5 MB)
  ushort* xh = weffbT + 3 * E * E;
  ushort* xl = xh + NX;
  ushort* qg = xl + NX;
  ushort* kg = qg + NX;
  ushort* vtg = kg + NX;

  xcast<<<dim3(NX / 1024), 256, 0, stream>>>(x, xh, xl);
  fold_tiled<<<dim3(E / 256, E / 8, 2), 256, 0, stream>>>(wq, wk, rot, ent,
                                                          weffbT);
  wv_cast<<<dim3(E * E / 1024), 256, 0, stream>>>(wv, weffbT + 2 * E * E);
  qkv_fused<<<dim3(H, BATCH * SEQ / 128), 512, 0, stream>>>(xh, xl, weffbT, qg,
                                                            kg, vtg);
  attn_mfma<<<dim3(SEQ / 128, BATCH * H), 512, 0, stream>>>(qg, kg, vtg, out);
}

// Round 8
// 231.191 us; speedup vs baseline: 1.1375x; 1.0075x over previous
//
#include <hip/hip_runtime.h>
#include <cstddef>

#define E 512
#define H 8
#define D 64
#define BATCH 2
#define SEQ 4096

typedef __attribute__((ext_vector_type(8))) short bf16x8;   // MFMA A/B frag
typedef __attribute__((ext_vector_type(4))) float f32x4;    // 16x16 C/D frag
typedef __attribute__((ext_vector_type(16))) float f32x16;  // 32x32 C/D frag
typedef __attribute__((ext_vector_type(4))) unsigned uint4v;

__device__ __forceinline__ ushort f2bf(float f) {
  unsigned u = __builtin_bit_cast(unsigned, f);
  u += 0x7fff + ((u >> 16) & 1);  // RNE
  return (ushort)(u >> 16);
}
__device__ __forceinline__ float bf2f(ushort h) {
  return __builtin_bit_cast(float, (unsigned)h << 16);
}
__device__ __forceinline__ unsigned pk_bf16(float lo, float hi) {
#if __has_builtin(__builtin_amdgcn_cvt_pk_bf16_f32)
  typedef __attribute__((ext_vector_type(2))) __bf16 bfv2;
  bfv2 r = __builtin_amdgcn_cvt_pk_bf16_f32(lo, hi);
  return __builtin_bit_cast(unsigned, r);
#else
  return (unsigned)f2bf(lo) | ((unsigned)f2bf(hi) << 16);
#endif
}
__device__ __forceinline__ float fexp2(float x) {
#if __has_builtin(__builtin_amdgcn_exp2f)
  return __builtin_amdgcn_exp2f(x);
#else
  return exp2f(x);
#endif
}
// lanes[32:63] of a  <->  lanes[0:31] of b. NON-volatile: scheduler may
// move it (we want softmax(t1) to slide under PV(t0) MFMAs).
__device__ __forceinline__ void permswap32(unsigned& a, unsigned& b) {
  asm("v_permlane32_swap_b32 %0, %1" : "+v"(a), "+v"(b));
}

// ---------------------------------------------------------------------------
// Kernel 0: cast x -> bf16 hi/lo split (xh + xl ~= x to ~16 mantissa bits)
// ---------------------------------------------------------------------------
__global__ __launch_bounds__(256) void xcast(const float* __restrict__ x,
                                             ushort* __restrict__ xh,
                                             ushort* __restrict__ xl) {
  size_t i = ((size_t)blockIdx.x * 256 + threadIdx.x) * 4;
  float4 v = *(const float4*)&x[i];
  ushort4 h, l;
  h.x = f2bf(v.x); l.x = f2bf(v.x - bf2f(h.x));
  h.y = f2bf(v.y); l.y = f2bf(v.y - bf2f(h.y));
  h.z = f2bf(v.z); l.z = f2bf(v.z - bf2f(h.z));
  h.w = f2bf(v.w); l.w = f2bf(v.w - bf2f(h.w));
  *(ushort4*)&xh[i] = h;
  *(ushort4*)&xl[i] = l;
}

// ---------------------------------------------------------------------------
// Kernel 1: fold weights (z=0: wq@rot, z=1: wk@ent) + wv cast (z=2).
// Split n-width 8->4 (grid.y 64->128): 2048 waves = 2/SIMD (was 1/SIMD,
// latency-exposed FMA chains); wv_cast merged as z==2 to save a launch.
// ---------------------------------------------------------------------------
__global__ __launch_bounds__(256) void fold_tiled(
    const float* __restrict__ wq, const float* __restrict__ wk,
    const float* __restrict__ rot, const float* __restrict__ ent,
    const float* __restrict__ wv, ushort* __restrict__ weffbT) {
  const int z = blockIdx.z;
  const int k = blockIdx.x * 256 + threadIdx.x;
  const int n0 = blockIdx.y * 4;
  if (z == 2) {  // pure cast: weffT[2][n][k] = bf16(wv[n][k])
#pragma unroll
    for (int t = 0; t < 4; ++t)
      weffbT[(size_t)2 * E * E + (size_t)(n0 + t) * E + k] =
          f2bf(wv[(size_t)(n0 + t) * E + k]);
    return;
  }
  const float* w = z ? wk : wq;
  const float* r = z ? ent : rot;
  float acc[4] = {};
  for (int j0 = 0; j0 < E; j0 += 16) {
    float wv_[16];
#pragma unroll
    for (int u = 0; u < 16; ++u) wv_[u] = w[(size_t)(j0 + u) * E + k];
#pragma unroll
    for (int u = 0; u < 16; ++u)
#pragma unroll
      for (int t = 0; t < 4; ++t)
        acc[t] += wv_[u] * r[(size_t)(j0 + u) * E + n0 + t];
  }
#pragma unroll
  for (int t = 0; t < 4; ++t)
    weffbT[(size_t)z * E * E + (size_t)(n0 + t) * E + k] = f2bf(acc[t]);
}

// ---------------------------------------------------------------------------
// Kernel 2: fused QKV GEMM, 32x32x16 MFMA, 8 waves (4m x 2n), M=128/block,
// XCD swizzle (kept: R7 rest -12.7µs). NEW this round: 2-DEEP prefetch.
// Old: tile k+1's loads issued after barrier-2, consumed at next barrier-1
// -> slack ~ one compute phase (~300cyc), marginal vs L2 latency (~200-400).
// New: two named register sets (no runtime-indexed arrays — rule #20),
// K-loop unrolled x2; set X's loads issue 2 sub-iters before the LDS write
// -> slack ~800cyc >> latency. +32 VGPR (est ~110/128 cap).
// ---------------------------------------------------------------------------
#define LDQ 72    // qkv LDS stride (ushort) = 144 B
#define LDS_S 136 // v-transpose buffer stride (ushort) = 272 B, 16B-aligned

__global__ __launch_bounds__(512, 4) void qkv_fused(
    const ushort* __restrict__ xhg, const ushort* __restrict__ xlg,
    const ushort* __restrict__ weffbT, ushort* __restrict__ qg,
    ushort* __restrict__ kg, ushort* __restrict__ vtg) {
  __shared__ ushort sm[(128 + 128 + 192) * LDQ];  // Ah | Al | B  (64.5 KB)
  ushort* Ah = sm;
  ushort* Al = sm + 128 * LDQ;
  ushort* Bs = sm + 256 * LDQ;
  ushort* vt_lds = Bs;  // epilogue reuse: 64*LDS_S = 8704 <= 192*72 = 13824

  // XCD swizzle: give each XCD a contiguous chunk of m-blocks (all heads)
  // so A-tiles stay in its private L2 (R7: verified via FETCH_SIZE drop).
  const int lin = blockIdx.y * 8 + blockIdx.x;  // 0..511
  const int nl = (lin & 7) * 64 + (lin >> 3);
  const int head = nl & 7;
  const int m0 = (nl >> 3) * 128;

  const int tid = threadIdx.x;
  const int wave = tid >> 6, lane = tid & 63;
  const int l31 = lane & 31, hi = lane >> 5;
  const int wm = wave & 3, wn = wave >> 2;

  const int ar = tid >> 2, ac8 = (tid & 3) * 8;
  const int b1r = tid >> 2;                 // B rows 0..127 (q|k)
  const int b2r = 128 + ((tid >> 2) & 63);  // B rows 128..191 (v)

  const ushort* arow = xhg + (size_t)(m0 + ar) * E + ac8;
  const ushort* lrow = xlg + (size_t)(m0 + ar) * E + ac8;
  const ushort* b1row =
      weffbT + (size_t)(b1r >> 6) * E * E + (size_t)(head * 64 + (b1r & 63)) * E + ac8;
  const ushort* b2row =
      weffbT + (size_t)2 * E * E + (size_t)(head * 64 + (b2r & 63)) * E + ac8;

  f32x16 acc[3];
  acc[0] = 0.f;
  acc[1] = 0.f;
  acc[2] = 0.f;

  const ushort* Ar = Ah + (wm * 32 + l31) * LDQ;
  const ushort* Lr = Al + (wm * 32 + l31) * LDQ;
  const ushort* Br = Bs + (wn * 96 + l31) * LDQ;

  auto compute = [&]() {
#pragma unroll
    for (int ks = 0; ks < 2; ++ks) {
      bf16x8 ah = *(const bf16x8*)&Ar[ks * 16 + hi * 8];
      bf16x8 al = *(const bf16x8*)&Lr[ks * 16 + hi * 8];
#pragma unroll
      for (int t = 0; t < 3; ++t) {
        bf16x8 bf = *(const bf16x8*)&Br[t * 32 * LDQ + ks * 16 + hi * 8];
        acc[t] =
            __builtin_amdgcn_mfma_f32_32x32x16_bf16(ah, bf, acc[t], 0, 0, 0);
        acc[t] =
            __builtin_amdgcn_mfma_f32_32x32x16_bf16(al, bf, acc[t], 0, 0, 0);
      }
    }
  };

  // 2-deep prefetch: set A = tile k0, set B = tile k0+32 (named regs).
  uint4 pa_hA = *(const uint4*)&arow[0];
  uint4 pa_lA = *(const uint4*)&lrow[0];
  uint4 pb1A = *(const uint4*)&b1row[0];
  uint4 pb2A = (tid < 256) ? *(const uint4*)&b2row[0] : uint4{0, 0, 0, 0};
  uint4 pa_hB = *(const uint4*)&arow[32];
  uint4 pa_lB = *(const uint4*)&lrow[32];
  uint4 pb1B = *(const uint4*)&b1row[32];
  uint4 pb2B = (tid < 256) ? *(const uint4*)&b2row[32] : uint4{0, 0, 0, 0};

  for (int k0 = 0; k0 < E; k0 += 64) {
    // ---- sub-iter A: tile k0 ----
    __syncthreads();
    *(uint4*)&Ah[ar * LDQ + ac8] = pa_hA;
    *(uint4*)&Al[ar * LDQ + ac8] = pa_lA;
    *(uint4*)&Bs[b1r * LDQ + ac8] = pb1A;
    if (tid < 256) *(uint4*)&Bs[b2r * LDQ + ac8] = pb2A;
    __syncthreads();
    {
      const int kA = (k0 + 64 < E) ? k0 + 64 : 0;  // next A-parity tile
      pa_hA = *(const uint4*)&arow[kA];
      pa_lA = *(const uint4*)&lrow[kA];
      pb1A = *(const uint4*)&b1row[kA];
      if (tid < 256) pb2A = *(const uint4*)&b2row[kA];
    }
    compute();

    // ---- sub-iter B: tile k0+32 ----
    __syncthreads();
    *(uint4*)&Ah[ar * LDQ + ac8] = pa_hB;
    *(uint4*)&Al[ar * LDQ + ac8] = pa_lB;
    *(uint4*)&Bs[b1r * LDQ + ac8] = pb1B;
    if (tid < 256) *(uint4*)&Bs[b2r * LDQ + ac8] = pb2B;
    __syncthreads();
    {
      const int kB = (k0 + 96 < E) ? k0 + 96 : 32;  // next B-parity tile
      pa_hB = *(const uint4*)&arow[kB];
      pa_lB = *(const uint4*)&lrow[kB];
      pb1B = *(const uint4*)&b1row[kB];
      if (tid < 256) pb2B = *(const uint4*)&b2row[kB];
    }
    compute();
  }

  const int b = m0 >> 12;
  const int s_base = m0 & (SEQ - 1);
  const float QSCALE = 0.125f * 1.44269504f;  // fold 1/sqrt(D)*log2(e) into q

  // ---- q / k tiles: pair-pack (d, d+1) via shfl_xor -> u32 stores ----
#pragma unroll
  for (int t = 0; t < 3; ++t) {
    const int n0 = wn * 96 + t * 32;
    const int w = n0 >> 6;  // 0:q 1:k 2:v
    if (w != 2) {
      ushort* dst = (w == 0) ? qg : kg;
      const float sc = (w == 0) ? QSCALE : 1.0f;
      const int d = (n0 & 63) + l31;
#pragma unroll
      for (int r = 0; r < 16; ++r) {
        float v = acc[t][r] * sc;
        float vo = __shfl_xor(v, 1);
        if (!(lane & 1)) {
          int s = s_base + wm * 32 + (r & 3) + 8 * (r >> 2) + 4 * hi;
          size_t ix = ((size_t)(b * H + head) * SEQ + s) * D + d;
          *(unsigned*)&dst[ix] = pk_bf16(v, vo);
        }
      }
    }
  }

  // ---- v tiles: transpose through LDS -> coalesced vt[bh][d][s] stores ----
  __syncthreads();  // all waves done reading Bs before overlay
  if (wn == 1) {
#pragma unroll
    for (int t = 1; t < 3; ++t) {
      const int d = (t - 1) * 32 + l31;
#pragma unroll
      for (int g = 0; g < 4; ++g) {
        uint2 w2;
        w2.x = pk_bf16(acc[t][g * 4 + 0], acc[t][g * 4 + 1]);
        w2.y = pk_bf16(acc[t][g * 4 + 2], acc[t][g * 4 + 3]);
        int s = wm * 32 + 8 * g + 4 * hi;
        *(uint2*)&vt_lds[d * LDS_S + s] = w2;
      }
    }
  }
  __syncthreads();
  {
    int vr = tid >> 3, vs = (tid & 7) * 16;  // d-row, 16-col s chunk
    uint4 c0 = *(const uint4*)&vt_lds[vr * LDS_S + vs];
    uint4 c1 = *(const uint4*)&vt_lds[vr * LDS_S + vs + 8];
    size_t vo = ((size_t)(b * H + head) * D + vr) * SEQ + s_base + vs;
    *(uint4*)&vtg[vo] = c0;
    *(uint4*)&vtg[vo + 8] = c1;
  }
}

// ---------------------------------------------------------------------------
// Kernel 3: flash attention — R6 version verbatim (94.6 µs verified).
// XCD swizzle REVERTED: R7 showed FETCH 70->12.6MB but dur +4.2µs — fetch
// volume was not on the critical path at 10% HBM; swizzle only perturbed
// scheduling. Plain qt/bh mapping restored.
// ---------------------------------------------------------------------------
#define LDK 72  // padded stride (bf16): 144B, 16B-aligned

__global__ __launch_bounds__(512, 4) void attn_mfma(
    const ushort* __restrict__ qg, const ushort* __restrict__ kg,
    const ushort* __restrict__ vtg, float* __restrict__ out) {
  __shared__ ushort sm[4 * 64 * LDK + 256];  // Ks[2] | Vs[2] | lex
  ushort* Ks0 = sm;
  ushort* Vs0 = sm + 2 * 64 * LDK;
  float* lex = (float*)(sm + 4 * 64 * LDK);  // 128 floats

  const int qt = blockIdx.x;  // 0..31 (128 q-rows each)
  const int bh = blockIdx.y;
  const int tid = threadIdx.x;
  const int wave = tid >> 6;  // 0..7
  const int grp = wave >> 2, wq = wave & 3;
  const int lane = tid & 63;
  const int l31 = lane & 31, hi = lane >> 5;
  const int gtid = tid & 255;  // tid within group

  const ushort* qp = qg + (size_t)bh * SEQ * D;
  const ushort* kp = kg + (size_t)bh * SEQ * D;
  const ushort* vp = vtg + (size_t)bh * D * SEQ;
  ushort* Ksg = Ks0 + grp * 64 * LDK;
  ushort* Vsg = Vs0 + grp * 64 * LDK;

  const int qrow0 = qt * 128 + wq * 32;
  // Q as B-operand: qf[ds] lane holds Q[qrow0+l31][ds*16 + hi*8 + j]
  bf16x8 qf[4];
#pragma unroll
  for (int ds = 0; ds < 4; ++ds)
    qf[ds] =
        *(const bf16x8*)&qp[(size_t)(qrow0 + l31) * D + ds * 16 + hi * 8];

  f32x16 o[2];
  o[0] = 0.f;
  o[1] = 0.f;
  float l_r = 0.f;  // per-lane partial row-sum for q = qrow0 + l31

  // staging: each group's 256 threads cover its 64x64 K and V tiles
  const int r0 = gtid >> 3, c0 = (gtid & 7) * 8;  // r0 in 0..31
  const int r1 = 32 + r0;

  // preload tile it=0 (kt = grp)
  uint4 pk0 = *(const uint4*)&kp[(size_t)(grp * 64 + r0) * D + c0];
  uint4 pk1 = *(const uint4*)&kp[(size_t)(grp * 64 + r1) * D + c0];
  uint4 pv0 = *(const uint4*)&vp[(size_t)r0 * SEQ + grp * 64 + c0];
  uint4 pv1 = *(const uint4*)&vp[(size_t)r1 * SEQ + grp * 64 + c0];

  for (int it = 0; it < SEQ / 128; ++it) {
    __syncthreads();  // prev iter's frag reads done (both groups)
    *(uint4*)&Ksg[r0 * LDK + c0] = pk0;
    *(uint4*)&Ksg[r1 * LDK + c0] = pk1;
    *(uint4*)&Vsg[r0 * LDK + c0] = pv0;
    *(uint4*)&Vsg[r1 * LDK + c0] = pv1;
    __syncthreads();

    // issue NEXT tile's loads; latency hides under this tile's compute
    {
      const int itn = (it + 1 < SEQ / 128) ? it + 1 : it;
      const int ktn = itn * 2 + grp;
      const ushort* ksrc = kp + (size_t)ktn * 64 * D;
      pk0 = *(const uint4*)&ksrc[r0 * D + c0];
      pk1 = *(const uint4*)&ksrc[r1 * D + c0];
      pv0 = *(const uint4*)&vp[(size_t)r0 * SEQ + ktn * 64 + c0];
      pv1 = *(const uint4*)&vp[(size_t)r1 * SEQ + ktn * 64 + c0];
    }

    __builtin_amdgcn_s_setprio(1);
    // ---- QK for BOTH 32-k subtiles, chains interleaved ----
    f32x16 st0 = 0.f, st1 = 0.f;
#pragma unroll
    for (int ds = 0; ds < 4; ++ds) {
      bf16x8 kf0 = *(const bf16x8*)&Ksg[(l31)*LDK + ds * 16 + hi * 8];
      bf16x8 kf1 = *(const bf16x8*)&Ksg[(32 + l31) * LDK + ds * 16 + hi * 8];
      st0 = __builtin_amdgcn_mfma_f32_32x32x16_bf16(kf0, qf[ds], st0, 0, 0, 0);
      st1 = __builtin_amdgcn_mfma_f32_32x32x16_bf16(kf1, qf[ds], st1, 0, 0, 0);
    }

    // ---- t = 0: softmax + P-frag build + PV ----
    bf16x8 pf00, pf01;
    {
      float pv[16];
#pragma unroll
      for (int r = 0; r < 16; ++r) pv[r] = fexp2(st0[r]);
      float s01 = (pv[0] + pv[1]) + (pv[2] + pv[3]);
      float s23 = (pv[4] + pv[5]) + (pv[6] + pv[7]);
      float s45 = (pv[8] + pv[9]) + (pv[10] + pv[11]);
      float s67 = (pv[12] + pv[13]) + (pv[14] + pv[15]);
      l_r += (s01 + s23) + (s45 + s67);
      unsigned w0[4], w1[4];
#pragma unroll
      for (int j = 0; j < 2; ++j) {
        {
          unsigned c0w = pk_bf16(pv[2 * j + 0], pv[2 * j + 1]);
          unsigned c1w = pk_bf16(pv[2 * j + 4], pv[2 * j + 5]);
          permswap32(c0w, c1w);
          w0[j] = c0w;
          w0[2 + j] = c1w;
        }
        {
          unsigned c0w = pk_bf16(pv[2 * j + 8], pv[2 * j + 9]);
          unsigned c1w = pk_bf16(pv[2 * j + 12], pv[2 * j + 13]);
          permswap32(c0w, c1w);
          w1[j] = c0w;
          w1[2 + j] = c1w;
        }
      }
      pf00 = __builtin_bit_cast(bf16x8, (uint4v){w0[0], w0[1], w0[2], w0[3]});
      pf01 = __builtin_bit_cast(bf16x8, (uint4v){w1[0], w1[1], w1[2], w1[3]});
    }
#pragma unroll
    for (int nt = 0; nt < 2; ++nt) {
      bf16x8 vf0 = *(const bf16x8*)&Vsg[(nt * 32 + l31) * LDK + hi * 8];
      o[nt] =
          __builtin_amdgcn_mfma_f32_32x32x16_bf16(pf00, vf0, o[nt], 0, 0, 0);
      bf16x8 vf1 = *(const bf16x8*)&Vsg[(nt * 32 + l31) * LDK + 16 + hi * 8];
      o[nt] =
          __builtin_amdgcn_mfma_f32_32x32x16_bf16(pf01, vf1, o[nt], 0, 0, 0);
    }

    // ---- t = 1: softmax (scheduler may overlap with PV(t0)) + PV ----
    bf16x8 pf10, pf11;
    {
      float pv[16];
#pragma unroll
      for (int r = 0; r < 16; ++r) pv[r] = fexp2(st1[r]);
      float s01 = (pv[0] + pv[1]) + (pv[2] + pv[3]);
      float s23 = (pv[4] + pv[5]) + (pv[6] + pv[7]);
      float s45 = (pv[8] + pv[9]) + (pv[10] + pv[11]);
      float s67 = (pv[12] + pv[13]) + (pv[14] + pv[15]);
      l_r += (s01 + s23) + (s45 + s67);
      unsigned w0[4], w1[4];
#pragma unroll
      for (int j = 0; j < 2; ++j) {
        {
          unsigned c0w = pk_bf16(pv[2 * j + 0], pv[2 * j + 1]);
          unsigned c1w = pk_bf16(pv[2 * j + 4], pv[2 * j + 5]);
          permswap32(c0w, c1w);
          w0[j] = c0w;
          w0[2 + j] = c1w;
        }
        {
          unsigned c0w = pk_bf16(pv[2 * j + 8], pv[2 * j + 9]);
          unsigned c1w = pk_bf16(pv[2 * j + 12], pv[2 * j + 13]);
          permswap32(c0w, c1w);
          w1[j] = c0w;
          w1[2 + j] = c1w;
        }
      }
      pf10 = __builtin_bit_cast(bf16x8, (uint4v){w0[0], w0[1], w0[2], w0[3]});
      pf11 = __builtin_bit_cast(bf16x8, (uint4v){w1[0], w1[1], w1[2], w1[3]});
    }
#pragma unroll
    for (int nt = 0; nt < 2; ++nt) {
      bf16x8 vf0 = *(const bf16x8*)&Vsg[(nt * 32 + l31) * LDK + 32 + hi * 8];
      o[nt] =
          __builtin_amdgcn_mfma_f32_32x32x16_bf16(pf10, vf0, o[nt], 0, 0, 0);
      bf16x8 vf1 = *(const bf16x8*)&Vsg[(nt * 32 + l31) * LDK + 48 + hi * 8];
      o[nt] =
          __builtin_amdgcn_mfma_f32_32x32x16_bf16(pf11, vf1, o[nt], 0, 0, 0);
    }
    __builtin_amdgcn_s_setprio(0);
  }

  // ---- combine the two K-halves (additive: no max bookkeeping) ----
  __syncthreads();  // all waves done with Ks/Vs before Oex overlay
  float lg = l_r + __shfl_xor(l_r, 32);  // lanes l/l+32 cover all 32 k-rows
  float* Oex = (float*)sm;               // [128 q][64 d], stride 68 floats
  if (grp == 1) {
#pragma unroll
    for (int nt = 0; nt < 2; ++nt)
#pragma unroll
      for (int r = 0; r < 16; ++r) {
        int row = (r & 3) + 8 * (r >> 2) + 4 * hi;
        Oex[(wq * 32 + row) * 68 + nt * 32 + l31] = o[nt][r];
      }
    if (lane < 32) lex[wq * 32 + l31] = lg;
  }
  __syncthreads();
  if (grp == 0) {
    float linv = 1.f / (lg + lex[wq * 32 + l31]);
    const int b = bh >> 3, h = bh & 7;
#pragma unroll
    for (int r = 0; r < 16; ++r) {
      int row = (r & 3) + 8 * (r >> 2) + 4 * hi;
      float inv = __shfl(linv, row);  // lane `row` owns q = qrow0 + row
      int srow = qt * 128 + wq * 32 + row;
#pragma unroll
      for (int nt = 0; nt < 2; ++nt) {
        float val = o[nt][r] + Oex[(wq * 32 + row) * 68 + nt * 32 + l31];
        out[((size_t)b * SEQ + srow) * E + h * D + nt * 32 + l31] = val * inv;
      }
    }
  }
}

// ---------------------------------------------------------------------------
extern "C" void kernel_launch(void* const* d_in, const int* in_sizes, int n_in,
                              void* d_out, int out_size, void* d_ws,
                              size_t ws_size, hipStream_t stream) {
  const float* rot = (const float*)d_in[0];
  const float* ent = (const float*)d_in[1];
  const float* x = (const float*)d_in[2];
  const float* wq = (const float*)d_in[3];
  const float* wk = (const float*)d_in[4];
  const float* wv = (const float*)d_in[5];
  float* out = (float*)d_out;

  const size_t NX = (size_t)BATCH * SEQ * E;  // 4M elements
  ushort* weffbT = (ushort*)d_ws;             // 3*E*E bf16 (1.5 MB)
  ushort* xh = weffbT + 3 * E * E;
  ushort* xl = xh + NX;
  ushort* qg = xl + NX;
  ushort* kg = qg + NX;
  ushort* vtg = kg + NX;

  xcast<<<dim3(NX / 1024), 256, 0, stream>>>(x, xh, xl);
  fold_tiled<<<dim3(E / 256, E / 4, 3), 256, 0, stream>>>(wq, wk, rot, ent, wv,
                                                          weffbT);
  qkv_fused<<<dim3(H, BATCH * SEQ / 128), 512, 0, stream>>>(xh, xl, weffbT, qg,
                                                            kg, vtg);
  attn_mfma<<<dim3(SEQ / 128, BATCH * H), 512, 0, stream>>>(qg, kg, vtg, out);
}

// Round 9
// 224.534 us; speedup vs baseline: 1.1712x; 1.0297x over previous
//
#include <hip/hip_runtime.h>
#include <cstddef>

#define E 512
#define H 8
#define D 64
#define BATCH 2
#define SEQ 4096

typedef __attribute__((ext_vector_type(8))) short bf16x8;   // MFMA A/B frag
typedef __attribute__((ext_vector_type(4))) float f32x4;    // 16x16 C/D frag
typedef __attribute__((ext_vector_type(16))) float f32x16;  // 32x32 C/D frag
typedef __attribute__((ext_vector_type(4))) unsigned uint4v;

__device__ __forceinline__ ushort f2bf(float f) {
  unsigned u = __builtin_bit_cast(unsigned, f);
  u += 0x7fff + ((u >> 16) & 1);  // RNE
  return (ushort)(u >> 16);
}
__device__ __forceinline__ float bf2f(ushort h) {
  return __builtin_bit_cast(float, (unsigned)h << 16);
}
__device__ __forceinline__ unsigned pk_bf16(float lo, float hi) {
#if __has_builtin(__builtin_amdgcn_cvt_pk_bf16_f32)
  typedef __attribute__((ext_vector_type(2))) __bf16 bfv2;
  bfv2 r = __builtin_amdgcn_cvt_pk_bf16_f32(lo, hi);
  return __builtin_bit_cast(unsigned, r);
#else
  return (unsigned)f2bf(lo) | ((unsigned)f2bf(hi) << 16);
#endif
}
__device__ __forceinline__ float fexp2(float x) {
#if __has_builtin(__builtin_amdgcn_exp2f)
  return __builtin_amdgcn_exp2f(x);
#else
  return exp2f(x);
#endif
}
// lanes[32:63] of a  <->  lanes[0:31] of b. NON-volatile: scheduler may
// move it (we want softmax(t1) to slide under PV(t0) MFMAs).
__device__ __forceinline__ void permswap32(unsigned& a, unsigned& b) {
  asm("v_permlane32_swap_b32 %0, %1" : "+v"(a), "+v"(b));
}

// hi/lo bf16 split of 8 floats -> packed uint4 words (same RNE ops as the
// old standalone xcast kernel -> bit-identical numerics).
__device__ __forceinline__ void cvt8_hl(float4 a, float4 b, uint4& hw,
                                        uint4& lw) {
  float v0 = a.x, v1 = a.y, v2 = a.z, v3 = a.w;
  float v4 = b.x, v5 = b.y, v6 = b.z, v7 = b.w;
  ushort h0 = f2bf(v0), h1 = f2bf(v1), h2 = f2bf(v2), h3 = f2bf(v3);
  ushort h4 = f2bf(v4), h5 = f2bf(v5), h6 = f2bf(v6), h7 = f2bf(v7);
  hw.x = (unsigned)h0 | ((unsigned)h1 << 16);
  hw.y = (unsigned)h2 | ((unsigned)h3 << 16);
  hw.z = (unsigned)h4 | ((unsigned)h5 << 16);
  hw.w = (unsigned)h6 | ((unsigned)h7 << 16);
  lw.x = (unsigned)f2bf(v0 - bf2f(h0)) | ((unsigned)f2bf(v1 - bf2f(h1)) << 16);
  lw.y = (unsigned)f2bf(v2 - bf2f(h2)) | ((unsigned)f2bf(v3 - bf2f(h3)) << 16);
  lw.z = (unsigned)f2bf(v4 - bf2f(h4)) | ((unsigned)f2bf(v5 - bf2f(h5)) << 16);
  lw.w = (unsigned)f2bf(v6 - bf2f(h6)) | ((unsigned)f2bf(v7 - bf2f(h7)) << 16);
}

// ---------------------------------------------------------------------------
// Kernel 1: fold weights (z=0: wq@rot, z=1: wk@ent) + wv cast (z=2).
// ---------------------------------------------------------------------------
__global__ __launch_bounds__(256) void fold_tiled(
    const float* __restrict__ wq, const float* __restrict__ wk,
    const float* __restrict__ rot, const float* __restrict__ ent,
    const float* __restrict__ wv, ushort* __restrict__ weffbT) {
  const int z = blockIdx.z;
  const int k = blockIdx.x * 256 + threadIdx.x;
  const int n0 = blockIdx.y * 4;
  if (z == 2) {  // pure cast: weffT[2][n][k] = bf16(wv[n][k])
#pragma unroll
    for (int t = 0; t < 4; ++t)
      weffbT[(size_t)2 * E * E + (size_t)(n0 + t) * E + k] =
          f2bf(wv[(size_t)(n0 + t) * E + k]);
    return;
  }
  const float* w = z ? wk : wq;
  const float* r = z ? ent : rot;
  float acc[4] = {};
  for (int j0 = 0; j0 < E; j0 += 16) {
    float wv_[16];
#pragma unroll
    for (int u = 0; u < 16; ++u) wv_[u] = w[(size_t)(j0 + u) * E + k];
#pragma unroll
    for (int u = 0; u < 16; ++u)
#pragma unroll
      for (int t = 0; t < 4; ++t)
        acc[t] += wv_[u] * r[(size_t)(j0 + u) * E + n0 + t];
  }
#pragma unroll
  for (int t = 0; t < 4; ++t)
    weffbT[(size_t)z * E * E + (size_t)(n0 + t) * E + k] = f2bf(acc[t]);
}

// ---------------------------------------------------------------------------
// Kernel 2: fused QKV GEMM, 32x32x16 MFMA, 8 waves (4m x 2n), M=128/block,
// XCD swizzle (kept: R7 verified). NEW this round: xcast FUSED into staging
// — x (f32) is loaded directly and hi/lo-split in registers (same bytes as
// xh+xl: 4B/elem), deleting the xcast kernel, its launch, and the 32MB
// xh/xl HBM round-trip. Prefetch reverted to 1-deep (2-deep measured +2.3).
// ---------------------------------------------------------------------------
#define LDQ 72    // qkv LDS stride (ushort) = 144 B
#define LDS_S 136 // v-transpose buffer stride (ushort) = 272 B, 16B-aligned

__global__ __launch_bounds__(512, 4) void qkv_fused(
    const float* __restrict__ xg, const ushort* __restrict__ weffbT,
    ushort* __restrict__ qg, ushort* __restrict__ kg,
    ushort* __restrict__ vtg) {
  __shared__ ushort sm[(128 + 128 + 192) * LDQ];  // Ah | Al | B  (64.5 KB)
  ushort* Ah = sm;
  ushort* Al = sm + 128 * LDQ;
  ushort* Bs = sm + 256 * LDQ;
  ushort* vt_lds = Bs;  // epilogue reuse: 64*LDS_S = 8704 <= 192*72 = 13824

  // XCD swizzle: give each XCD a contiguous chunk of m-blocks (all heads)
  // so A-tiles stay in its private L2 (R7: verified via FETCH_SIZE drop).
  const int lin = blockIdx.y * 8 + blockIdx.x;  // 0..511
  const int nl = (lin & 7) * 64 + (lin >> 3);
  const int head = nl & 7;
  const int m0 = (nl >> 3) * 128;

  const int tid = threadIdx.x;
  const int wave = tid >> 6, lane = tid & 63;
  const int l31 = lane & 31, hi = lane >> 5;
  const int wm = wave & 3, wn = wave >> 2;

  const int ar = tid >> 2, ac8 = (tid & 3) * 8;
  const int b1r = tid >> 2;                 // B rows 0..127 (q|k)
  const int b2r = 128 + ((tid >> 2) & 63);  // B rows 128..191 (v)

  const float* xrow = xg + (size_t)(m0 + ar) * E + ac8;
  const ushort* b1row =
      weffbT + (size_t)(b1r >> 6) * E * E + (size_t)(head * 64 + (b1r & 63)) * E + ac8;
  const ushort* b2row =
      weffbT + (size_t)2 * E * E + (size_t)(head * 64 + (b2r & 63)) * E + ac8;

  f32x16 acc[3];
  acc[0] = 0.f;
  acc[1] = 0.f;
  acc[2] = 0.f;

  const ushort* Ar = Ah + (wm * 32 + l31) * LDQ;
  const ushort* Lr = Al + (wm * 32 + l31) * LDQ;
  const ushort* Br = Bs + (wn * 96 + l31) * LDQ;

  // preload tile k0 = 0
  float4 xv0 = *(const float4*)&xrow[0];
  float4 xv1 = *(const float4*)&xrow[4];
  uint4 pb1 = *(const uint4*)&b1row[0];
  uint4 pb2 = (tid < 256) ? *(const uint4*)&b2row[0] : uint4{0, 0, 0, 0};

  for (int k0 = 0; k0 < E; k0 += 32) {
    __syncthreads();  // prev iter's frag reads done
    {
      uint4 hw, lw;
      cvt8_hl(xv0, xv1, hw, lw);
      *(uint4*)&Ah[ar * LDQ + ac8] = hw;
      *(uint4*)&Al[ar * LDQ + ac8] = lw;
    }
    *(uint4*)&Bs[b1r * LDQ + ac8] = pb1;
    if (tid < 256) *(uint4*)&Bs[b2r * LDQ + ac8] = pb2;
    __syncthreads();

    // issue NEXT tile's loads; latency hides under the MFMAs below
    const int kn = (k0 + 32 < E) ? k0 + 32 : 0;
    xv0 = *(const float4*)&xrow[kn];
    xv1 = *(const float4*)&xrow[kn + 4];
    pb1 = *(const uint4*)&b1row[kn];
    if (tid < 256) pb2 = *(const uint4*)&b2row[kn];

#pragma unroll
    for (int ks = 0; ks < 2; ++ks) {
      bf16x8 ah = *(const bf16x8*)&Ar[ks * 16 + hi * 8];
      bf16x8 al = *(const bf16x8*)&Lr[ks * 16 + hi * 8];
#pragma unroll
      for (int t = 0; t < 3; ++t) {
        bf16x8 bf = *(const bf16x8*)&Br[t * 32 * LDQ + ks * 16 + hi * 8];
        acc[t] =
            __builtin_amdgcn_mfma_f32_32x32x16_bf16(ah, bf, acc[t], 0, 0, 0);
        acc[t] =
            __builtin_amdgcn_mfma_f32_32x32x16_bf16(al, bf, acc[t], 0, 0, 0);
      }
    }
  }

  const int b = m0 >> 12;
  const int s_base = m0 & (SEQ - 1);
  const float QSCALE = 0.125f * 1.44269504f;  // fold 1/sqrt(D)*log2(e) into q

  // ---- q / k tiles: pair-pack (d, d+1) via shfl_xor -> u32 stores ----
#pragma unroll
  for (int t = 0; t < 3; ++t) {
    const int n0 = wn * 96 + t * 32;
    const int w = n0 >> 6;  // 0:q 1:k 2:v
    if (w != 2) {
      ushort* dst = (w == 0) ? qg : kg;
      const float sc = (w == 0) ? QSCALE : 1.0f;
      const int d = (n0 & 63) + l31;
#pragma unroll
      for (int r = 0; r < 16; ++r) {
        float v = acc[t][r] * sc;
        float vo = __shfl_xor(v, 1);
        if (!(lane & 1)) {
          int s = s_base + wm * 32 + (r & 3) + 8 * (r >> 2) + 4 * hi;
          size_t ix = ((size_t)(b * H + head) * SEQ + s) * D + d;
          *(unsigned*)&dst[ix] = pk_bf16(v, vo);
        }
      }
    }
  }

  // ---- v tiles: transpose through LDS -> coalesced vt[bh][d][s] stores ----
  __syncthreads();  // all waves done reading Bs before overlay
  if (wn == 1) {
#pragma unroll
    for (int t = 1; t < 3; ++t) {
      const int d = (t - 1) * 32 + l31;
#pragma unroll
      for (int g = 0; g < 4; ++g) {
        uint2 w2;
        w2.x = pk_bf16(acc[t][g * 4 + 0], acc[t][g * 4 + 1]);
        w2.y = pk_bf16(acc[t][g * 4 + 2], acc[t][g * 4 + 3]);
        int s = wm * 32 + 8 * g + 4 * hi;
        *(uint2*)&vt_lds[d * LDS_S + s] = w2;
      }
    }
  }
  __syncthreads();
  {
    int vr = tid >> 3, vs = (tid & 7) * 16;  // d-row, 16-col s chunk
    uint4 c0 = *(const uint4*)&vt_lds[vr * LDS_S + vs];
    uint4 c1 = *(const uint4*)&vt_lds[vr * LDS_S + vs + 8];
    size_t vo = ((size_t)(b * H + head) * D + vr) * SEQ + s_base + vs;
    *(uint4*)&vtg[vo] = c0;
    *(uint4*)&vtg[vo + 8] = c1;
  }
}

// ---------------------------------------------------------------------------
// Kernel 3: flash attention — R6/R8 version verbatim (94.7 µs verified).
// ---------------------------------------------------------------------------
#define LDK 72  // padded stride (bf16): 144B, 16B-aligned

__global__ __launch_bounds__(512, 4) void attn_mfma(
    const ushort* __restrict__ qg, const ushort* __restrict__ kg,
    const ushort* __restrict__ vtg, float* __restrict__ out) {
  __shared__ ushort sm[4 * 64 * LDK + 256];  // Ks[2] | Vs[2] | lex
  ushort* Ks0 = sm;
  ushort* Vs0 = sm + 2 * 64 * LDK;
  float* lex = (float*)(sm + 4 * 64 * LDK);  // 128 floats

  const int qt = blockIdx.x;  // 0..31 (128 q-rows each)
  const int bh = blockIdx.y;
  const int tid = threadIdx.x;
  const int wave = tid >> 6;  // 0..7
  const int grp = wave >> 2, wq = wave & 3;
  const int lane = tid & 63;
  const int l31 = lane & 31, hi = lane >> 5;
  const int gtid = tid & 255;  // tid within group

  const ushort* qp = qg + (size_t)bh * SEQ * D;
  const ushort* kp = kg + (size_t)bh * SEQ * D;
  const ushort* vp = vtg + (size_t)bh * D * SEQ;
  ushort* Ksg = Ks0 + grp * 64 * LDK;
  ushort* Vsg = Vs0 + grp * 64 * LDK;

  const int qrow0 = qt * 128 + wq * 32;
  // Q as B-operand: qf[ds] lane holds Q[qrow0+l31][ds*16 + hi*8 + j]
  bf16x8 qf[4];
#pragma unroll
  for (int ds = 0; ds < 4; ++ds)
    qf[ds] =
        *(const bf16x8*)&qp[(size_t)(qrow0 + l31) * D + ds * 16 + hi * 8];

  f32x16 o[2];
  o[0] = 0.f;
  o[1] = 0.f;
  float l_r = 0.f;  // per-lane partial row-sum for q = qrow0 + l31

  // staging: each group's 256 threads cover its 64x64 K and V tiles
  const int r0 = gtid >> 3, c0 = (gtid & 7) * 8;  // r0 in 0..31
  const int r1 = 32 + r0;

  // preload tile it=0 (kt = grp)
  uint4 pk0 = *(const uint4*)&kp[(size_t)(grp * 64 + r0) * D + c0];
  uint4 pk1 = *(const uint4*)&kp[(size_t)(grp * 64 + r1) * D + c0];
  uint4 pv0 = *(const uint4*)&vp[(size_t)r0 * SEQ + grp * 64 + c0];
  uint4 pv1 = *(const uint4*)&vp[(size_t)r1 * SEQ + grp * 64 + c0];

  for (int it = 0; it < SEQ / 128; ++it) {
    __syncthreads();  // prev iter's frag reads done (both groups)
    *(uint4*)&Ksg[r0 * LDK + c0] = pk0;
    *(uint4*)&Ksg[r1 * LDK + c0] = pk1;
    *(uint4*)&Vsg[r0 * LDK + c0] = pv0;
    *(uint4*)&Vsg[r1 * LDK + c0] = pv1;
    __syncthreads();

    // issue NEXT tile's loads; latency hides under this tile's compute
    {
      const int itn = (it + 1 < SEQ / 128) ? it + 1 : it;
      const int ktn = itn * 2 + grp;
      const ushort* ksrc = kp + (size_t)ktn * 64 * D;
      pk0 = *(const uint4*)&ksrc[r0 * D + c0];
      pk1 = *(const uint4*)&ksrc[r1 * D + c0];
      pv0 = *(const uint4*)&vp[(size_t)r0 * SEQ + ktn * 64 + c0];
      pv1 = *(const uint4*)&vp[(size_t)r1 * SEQ + ktn * 64 + c0];
    }

    __builtin_amdgcn_s_setprio(1);
    // ---- QK for BOTH 32-k subtiles, chains interleaved ----
    f32x16 st0 = 0.f, st1 = 0.f;
#pragma unroll
    for (int ds = 0; ds < 4; ++ds) {
      bf16x8 kf0 = *(const bf16x8*)&Ksg[(l31)*LDK + ds * 16 + hi * 8];
      bf16x8 kf1 = *(const bf16x8*)&Ksg[(32 + l31) * LDK + ds * 16 + hi * 8];
      st0 = __builtin_amdgcn_mfma_f32_32x32x16_bf16(kf0, qf[ds], st0, 0, 0, 0);
      st1 = __builtin_amdgcn_mfma_f32_32x32x16_bf16(kf1, qf[ds], st1, 0, 0, 0);
    }

    // ---- t = 0: softmax + P-frag build + PV ----
    bf16x8 pf00, pf01;
    {
      float pv[16];
#pragma unroll
      for (int r = 0; r < 16; ++r) pv[r] = fexp2(st0[r]);
      float s01 = (pv[0] + pv[1]) + (pv[2] + pv[3]);
      float s23 = (pv[4] + pv[5]) + (pv[6] + pv[7]);
      float s45 = (pv[8] + pv[9]) + (pv[10] + pv[11]);
      float s67 = (pv[12] + pv[13]) + (pv[14] + pv[15]);
      l_r += (s01 + s23) + (s45 + s67);
      unsigned w0[4], w1[4];
#pragma unroll
      for (int j = 0; j < 2; ++j) {
        {
          unsigned c0w = pk_bf16(pv[2 * j + 0], pv[2 * j + 1]);
          unsigned c1w = pk_bf16(pv[2 * j + 4], pv[2 * j + 5]);
          permswap32(c0w, c1w);
          w0[j] = c0w;
          w0[2 + j] = c1w;
        }
        {
          unsigned c0w = pk_bf16(pv[2 * j + 8], pv[2 * j + 9]);
          unsigned c1w = pk_bf16(pv[2 * j + 12], pv[2 * j + 13]);
          permswap32(c0w, c1w);
          w1[j] = c0w;
          w1[2 + j] = c1w;
        }
      }
      pf00 = __builtin_bit_cast(bf16x8, (uint4v){w0[0], w0[1], w0[2], w0[3]});
      pf01 = __builtin_bit_cast(bf16x8, (uint4v){w1[0], w1[1], w1[2], w1[3]});
    }
#pragma unroll
    for (int nt = 0; nt < 2; ++nt) {
      bf16x8 vf0 = *(const bf16x8*)&Vsg[(nt * 32 + l31) * LDK + hi * 8];
      o[nt] =
          __builtin_amdgcn_mfma_f32_32x32x16_bf16(pf00, vf0, o[nt], 0, 0, 0);
      bf16x8 vf1 = *(const bf16x8*)&Vsg[(nt * 32 + l31) * LDK + 16 + hi * 8];
      o[nt] =
          __builtin_amdgcn_mfma_f32_32x32x16_bf16(pf01, vf1, o[nt], 0, 0, 0);
    }

    // ---- t = 1: softmax (scheduler may overlap with PV(t0)) + PV ----
    bf16x8 pf10, pf11;
    {
      float pv[16];
#pragma unroll
      for (int r = 0; r < 16; ++r) pv[r] = fexp2(st1[r]);
      float s01 = (pv[0] + pv[1]) + (pv[2] + pv[3]);
      float s23 = (pv[4] + pv[5]) + (pv[6] + pv[7]);
      float s45 = (pv[8] + pv[9]) + (pv[10] + pv[11]);
      float s67 = (pv[12] + pv[13]) + (pv[14] + pv[15]);
      l_r += (s01 + s23) + (s45 + s67);
      unsigned w0[4], w1[4];
#pragma unroll
      for (int j = 0; j < 2; ++j) {
        {
          unsigned c0w = pk_bf16(pv[2 * j + 0], pv[2 * j + 1]);
          unsigned c1w = pk_bf16(pv[2 * j + 4], pv[2 * j + 5]);
          permswap32(c0w, c1w);
          w0[j] = c0w;
          w0[2 + j] = c1w;
        }
        {
          unsigned c0w = pk_bf16(pv[2 * j + 8], pv[2 * j + 9]);
          unsigned c1w = pk_bf16(pv[2 * j + 12], pv[2 * j + 13]);
          permswap32(c0w, c1w);
          w1[j] = c0w;
          w1[2 + j] = c1w;
        }
      }
      pf10 = __builtin_bit_cast(bf16x8, (uint4v){w0[0], w0[1], w0[2], w0[3]});
      pf11 = __builtin_bit_cast(bf16x8, (uint4v){w1[0], w1[1], w1[2], w1[3]});
    }
#pragma unroll
    for (int nt = 0; nt < 2; ++nt) {
      bf16x8 vf0 = *(const bf16x8*)&Vsg[(nt * 32 + l31) * LDK + 32 + hi * 8];
      o[nt] =
          __builtin_amdgcn_mfma_f32_32x32x16_bf16(pf10, vf0, o[nt], 0, 0, 0);
      bf16x8 vf1 = *(const bf16x8*)&Vsg[(nt * 32 + l31) * LDK + 48 + hi * 8];
      o[nt] =
          __builtin_amdgcn_mfma_f32_32x32x16_bf16(pf11, vf1, o[nt], 0, 0, 0);
    }
    __builtin_amdgcn_s_setprio(0);
  }

  // ---- combine the two K-halves (additive: no max bookkeeping) ----
  __syncthreads();  // all waves done with Ks/Vs before Oex overlay
  float lg = l_r + __shfl_xor(l_r, 32);  // lanes l/l+32 cover all 32 k-rows
  float* Oex = (float*)sm;               // [128 q][64 d], stride 68 floats
  if (grp == 1) {
#pragma unroll
    for (int nt = 0; nt < 2; ++nt)
#pragma unroll
      for (int r = 0; r < 16; ++r) {
        int row = (r & 3) + 8 * (r >> 2) + 4 * hi;
        Oex[(wq * 32 + row) * 68 + nt * 32 + l31] = o[nt][r];
      }
    if (lane < 32) lex[wq * 32 + l31] = lg;
  }
  __syncthreads();
  if (grp == 0) {
    float linv = 1.f / (lg + lex[wq * 32 + l31]);
    const int b = bh >> 3, h = bh & 7;
#pragma unroll
    for (int r = 0; r < 16; ++r) {
      int row = (r & 3) + 8 * (r >> 2) + 4 * hi;
      float inv = __shfl(linv, row);  // lane `row` owns q = qrow0 + row
      int srow = qt * 128 + wq * 32 + row;
#pragma unroll
      for (int nt = 0; nt < 2; ++nt) {
        float val = o[nt][r] + Oex[(wq * 32 + row) * 68 + nt * 32 + l31];
        out[((size_t)b * SEQ + srow) * E + h * D + nt * 32 + l31] = val * inv;
      }
    }
  }
}

// ---------------------------------------------------------------------------
extern "C" void kernel_launch(void* const* d_in, const int* in_sizes, int n_in,
                              void* d_out, int out_size, void* d_ws,
                              size_t ws_size, hipStream_t stream) {
  const float* rot = (const float*)d_in[0];
  const float* ent = (const float*)d_in[1];
  const float* x = (const float*)d_in[2];
  const float* wq = (const float*)d_in[3];
  const float* wk = (const float*)d_in[4];
  const float* wv = (const float*)d_in[5];
  float* out = (float*)d_out;

  const size_t NX = (size_t)BATCH * SEQ * E;  // 4M elements
  ushort* weffbT = (ushort*)d_ws;             // 3*E*E bf16 (1.5 MB)
  ushort* qg = weffbT + 3 * E * E;
  ushort* kg = qg + NX;
  ushort* vtg = kg + NX;

  fold_tiled<<<dim3(E / 256, E / 4, 3), 256, 0, stream>>>(wq, wk, rot, ent, wv,
                                                          weffbT);
  qkv_fused<<<dim3(H, BATCH * SEQ / 128), 512, 0, stream>>>(x, weffbT, qg, kg,
                                                            vtg);
  attn_mfma<<<dim3(SEQ / 128, BATCH * H), 512, 0, stream>>>(qg, kg, vtg, out);
}